// Round 12
// baseline (278.319 us; speedup 1.0000x reference)
//
#include <hip/hip_runtime.h>
#include <hip/hip_bf16.h>
#include <math.h>

#define TV_ 1600
#define SCALE_K 2.885390081777927f   // 2*log2(e): folded into fk/pk rows so tanh uses exp2 directly
#define RS2_ 0.70710678118654752f    // DKH^-0.5 folded into fq/pq rows

typedef __attribute__((ext_vector_type(8))) short bf16x8;
typedef __attribute__((ext_vector_type(4))) float f32x4;
typedef __attribute__((ext_vector_type(2))) __fp16 h2f;

__device__ __forceinline__ float tanh_scaled(float y) {
    y = fminf(44.f, fmaxf(-44.f, y));
    float e = __builtin_amdgcn_exp2f(y);
    float r = __builtin_amdgcn_rcpf(e + 1.f);
    return __builtin_fmaf(e, r, -r);
}

__device__ __forceinline__ ushort f2bf(float f) {
    __hip_bfloat16 h = __float2bfloat16(f);
    return *(ushort*)&h;
}
__device__ __forceinline__ float bf2f(ushort u) {
    uint w = ((uint)u) << 16;
    return __uint_as_float(w);
}

// ---------------------------------------------------------------------------
// T1 (fused): bx<25: transpose slice -> rt[n][tv][ci]=bf16(x) + Sbuf[n][ci]
// atomics (full x channel sums). bx==25: prep (wb/wq/qb/pet). bx==26: edge
// t-slice sums Tt[n][ci][slot] (t in {0..3}->slot, {60..63}->slot-56+4... see
// below) for the analytic conv-sum.
// ---------------------------------------------------------------------------
__global__ __launch_bounds__(256) void t1_kernel(
    const float* __restrict__ x, const float* __restrict__ pe,
    const float* __restrict__ tcn_w, const float* __restrict__ tg,
    const float* __restrict__ qkv_w, const float* __restrict__ qkv_b,
    ushort* __restrict__ rt, float* __restrict__ Sbuf, float* __restrict__ Tt,
    ushort* __restrict__ wb, ushort* __restrict__ wq, float* __restrict__ qb,
    ushort* __restrict__ pet)
{
    const int tid = threadIdx.x;
    const int bx = blockIdx.x, by = blockIdx.y;

    if (bx == 25) {   // prep slice
        #pragma unroll 1
        for (int j = 0; j < 9; ++j) {
            int idx = by * 256 + tid + j * 16384;
            if (idx < 27648) {
                int oc = idx / 576, kk = idx - oc * 576;
                int kt = kk >> 6, ci = kk & 63;
                float a = tg[oc] * rsqrtf(1.f + 1e-5f);
                wb[idx] = f2bf(tcn_w[(oc * 64 + ci) * 9 + kt] * a);
            } else if (idx < 32768) {
                int i2 = idx - 27648;
                int r = i2 >> 6, c = i2 & 63;
                int src; float sc;
                if (r < 16)      { src = r;      sc = RS2_; }
                else if (r < 32) { src = r;      sc = SCALE_K; }
                else if (r < 48) { src = r + 16; sc = 1.f; }
                else if (r < 64) { src = r - 48; sc = RS2_; }
                else             { src = r - 48; sc = SCALE_K; }
                wq[i2] = f2bf(qkv_w[src * 64 + c] * sc);
            } else if (idx < 32848) {
                int r = idx - 32768;
                int src; float sc;
                if (r < 16)      { src = r;      sc = RS2_; }
                else if (r < 32) { src = r;      sc = SCALE_K; }
                else if (r < 48) { src = r + 16; sc = 1.f; }
                else if (r < 64) { src = r - 48; sc = RS2_; }
                else             { src = r - 48; sc = SCALE_K; }
                qb[r] = qkv_b[src] * sc;
            } else if (idx < 135248) {
                int i3 = idx - 32848;
                int ci = i3 / 1600, tv = i3 - ci * 1600;
                pet[tv * 64 + ci] = f2bf(pe[ci * 1600 + tv]);
            }
        }
        return;
    }
    if (bx == 26) {   // edge t-slice sums: slot 0..3 -> t=slot; slot 4..7 -> t=56+slot
        const int n = by;
        #pragma unroll
        for (int it = 0; it < 2; ++it) {
            int item = tid + it * 256;               // 512 items = 64 ci x 8 slots
            int ci = item >> 3, slot = item & 7;
            int t = (slot < 4) ? slot : (56 + slot); // 0..3, 60..63
            const float* xp = x + (n * 64 + ci) * TV_ + t * 25;
            float s = 0.f;
            #pragma unroll
            for (int v = 0; v < 25; ++v) s += xp[v];
            Tt[(n * 64 + ci) * 8 + slot] = s;
        }
        return;
    }

    // transpose slice
    __shared__ ushort smt[64 * 66];
    const int tv0 = bx * 64;
    const int n = by;
    const int tvl = tid & 63, cig = tid >> 6;
    const int tv = tv0 + tvl;

    float psum[16];
    #pragma unroll
    for (int k = 0; k < 16; ++k) psum[k] = 0.f;
    #pragma unroll
    for (int k = 0; k < 16; ++k) {
        int ci = k * 4 + cig;
        float xv = x[(n * 64 + ci) * TV_ + tv];
        smt[tvl * 66 + ci] = f2bf(xv);
        psum[k] += xv;
    }
    #pragma unroll
    for (int k = 0; k < 16; ++k) {
        float s = psum[k];
        #pragma unroll
        for (int off = 32; off >= 1; off >>= 1) s += __shfl_down(s, off, 64);
        if (tvl == 0) atomicAdd(&Sbuf[n * 64 + k * 4 + cig], s);
    }
    __syncthreads();

    #pragma unroll
    for (int j = 0; j < 8; ++j) {
        int chunk = tid + j * 256;
        int tvr = chunk >> 5, p = chunk & 31;
        uint val = *(const uint*)&smt[tvr * 66 + p * 2];
        *(uint*)&rt[(n * TV_ + tv0 + tvr) * 64 + p * 2] = val;
    }
}

// ---------------------------------------------------------------------------
// K1: score kernel. 800 blocks x 2 (n,v) pairs (all co-resident -> no tail
// cohort). Body identical to round 11 per pair.
// ---------------------------------------------------------------------------
__global__ __launch_bounds__(256, 5) void score_kernel(
    const ushort* __restrict__ rt, const ushort* __restrict__ pet,
    const float* __restrict__ dbg, const float* __restrict__ dbb,
    const ushort* __restrict__ wq, const float* __restrict__ qb,
    const float* __restrict__ attn_w, const float* __restrict__ attn_b,
    float* __restrict__ aoc, float* __restrict__ se)
{
    __shared__ float sm[5312];
    ushort* smu = (ushort*)sm;
    const int MU_ = 1056, AO = 1120;
    const int FKP = 2400, PKP = 2976, FVP = 3552, PQP = 4128, FQP = 4704;

    const int tid = threadIdx.x;
    const int lane = tid & 63, wave = tid >> 6;
    const int m16 = lane & 15, q = lane >> 4;

    #pragma unroll 1
    for (int it = 0; it < 2; ++it) {
        if (it) __syncthreads();
        const int l = blockIdx.x * 2 + it;
        const int n = l / 25, v = l % 25;

        // phase 1: build xn/yb bf16 planes from rt + pet
        {
            const int part = tid & 7;
            const int ci0 = part * 8;
            const float rs = rsqrtf(1.f + 1e-5f);
            float sc8[8], sh8[8];
            #pragma unroll
            for (int i = 0; i < 8; ++i) {
                sc8[i] = dbg[(ci0 + i) * 25 + v] * rs;
                sh8[i] = dbb[(ci0 + i) * 25 + v];
            }
            #pragma unroll
            for (int j = 0; j < 2; ++j) {
                int t = (tid + j * 256) >> 3;
                uint4 xr = *(const uint4*)&rt[(n * TV_ + t * 25 + v) * 64 + ci0];
                uint4 pr = *(const uint4*)&pet[(t * 25 + v) * 64 + ci0];
                const ushort* xu = (const ushort*)&xr;
                const ushort* pu = (const ushort*)&pr;
                ushort xs[8], ys[8];
                #pragma unroll
                for (int i = 0; i < 8; ++i) {
                    float xf = bf2f(xu[i]);
                    xs[i] = f2bf(xf * sc8[i] + sh8[i]);
                    ys[i] = f2bf(xf + bf2f(pu[i]));
                }
                *(uint4*)&smu[t * 72 + ci0] = *(uint4*)xs;
                *(uint4*)&smu[4608 + t * 72 + ci0] = *(uint4*)ys;
            }
        }
        __syncthreads();

        // phase 2: qkv MFMA
        f32x4 acc[5];
        #pragma unroll
        for (int mt = 0; mt < 5; ++mt) acc[mt] = (f32x4){0.f, 0.f, 0.f, 0.f};
        #pragma unroll
        for (int kt = 0; kt < 2; ++kt) {
            const int koff = kt * 32 + q * 8;
            bf16x8 bx = *(const bf16x8*)&smu[(wave * 16 + m16) * 72 + koff];
            bf16x8 by = *(const bf16x8*)&smu[4608 + (wave * 16 + m16) * 72 + koff];
            #pragma unroll
            for (int mt = 0; mt < 5; ++mt) {
                bf16x8 a = *(const bf16x8*)&wq[(mt * 16 + m16) * 64 + koff];
                acc[mt] = __builtin_amdgcn_mfma_f32_16x16x32_bf16(a, (mt < 3) ? bx : by, acc[mt], 0, 0, 0);
            }
        }
        __syncthreads();

        // phase 2b
        {
            const int t = wave * 16 + m16;
            #pragma unroll
            for (int r = 0; r < 4; ++r)
                sm[(q * 4 + r) * 66 + t] = acc[0][r] + qb[q * 4 + r];
            *(h2f*)&sm[FKP + t * 9 + 2 * q] =
                __builtin_amdgcn_cvt_pkrtz(acc[1][0] + qb[16 + q * 4], acc[1][1] + qb[16 + q * 4 + 1]);
            *(h2f*)&sm[FKP + t * 9 + 2 * q + 1] =
                __builtin_amdgcn_cvt_pkrtz(acc[1][2] + qb[16 + q * 4 + 2], acc[1][3] + qb[16 + q * 4 + 3]);
            *(h2f*)&sm[FVP + t * 9 + 2 * q] =
                __builtin_amdgcn_cvt_pkrtz(acc[2][0] + qb[32 + q * 4], acc[2][1] + qb[32 + q * 4 + 1]);
            *(h2f*)&sm[FVP + t * 9 + 2 * q + 1] =
                __builtin_amdgcn_cvt_pkrtz(acc[2][2] + qb[32 + q * 4 + 2], acc[2][3] + qb[32 + q * 4 + 3]);
            *(h2f*)&sm[PQP + t * 9 + 2 * q] =
                __builtin_amdgcn_cvt_pkrtz(acc[3][0] + qb[48 + q * 4], acc[3][1] + qb[48 + q * 4 + 1]);
            *(h2f*)&sm[PQP + t * 9 + 2 * q + 1] =
                __builtin_amdgcn_cvt_pkrtz(acc[3][2] + qb[48 + q * 4 + 2], acc[3][3] + qb[48 + q * 4 + 3]);
            *(h2f*)&sm[PKP + t * 9 + 2 * q] =
                __builtin_amdgcn_cvt_pkrtz(acc[4][0] + qb[64 + q * 4], acc[4][1] + qb[64 + q * 4 + 1]);
            *(h2f*)&sm[PKP + t * 9 + 2 * q + 1] =
                __builtin_amdgcn_cvt_pkrtz(acc[4][2] + qb[64 + q * 4 + 2], acc[4][3] + qb[64 + q * 4 + 3]);
        }
        __syncthreads();

        // mu
        if (tid < 64) {
            int ch = tid & 15, qq = tid >> 4;
            float s = 0.f;
            #pragma unroll
            for (int t = 0; t < 16; ++t) s += sm[ch * 66 + qq * 16 + t];
            sm[MU_ + qq * 16 + ch] = s;
        }
        __syncthreads();
        if (tid < 16) {
            float mval = (sm[MU_ + tid] + sm[MU_ + 16 + tid] + sm[MU_ + 32 + tid] + sm[MU_ + 48 + tid]) * (1.f / 64.f);
            sm[MU_ + tid] = mval;
        }
        __syncthreads();

        // fqc pack
        #pragma unroll
        for (int e = 0; e < 2; ++e) {
            int idx = tid * 2 + e;
            int s = idx >> 3, h = idx & 7;
            float a = sm[(2 * h) * 66 + s] - sm[MU_ + 2 * h];
            float c = sm[(2 * h + 1) * 66 + s] - sm[MU_ + 2 * h + 1];
            *(h2f*)&sm[FQP + s * 9 + h] = __builtin_amdgcn_cvt_pkrtz(a, c);
        }
        __syncthreads();

        // phase 3
        const int g3 = tid & 7, m3 = tid >> 3;
        #pragma unroll 1
        for (int h = 0; h < 8; ++h) {
            const float mu0 = sm[MU_ + 2 * h], mu1 = sm[MU_ + 2 * h + 1];
            float fq0c[2], fq1c[2], pq0[2], pq1[2];
            #pragma unroll
            for (int js = 0; js < 2; ++js) {
                int s = 2 * m3 + js;
                h2f fq2 = *(const h2f*)&sm[FQP + s * 9 + h];
                h2f pq2 = *(const h2f*)&sm[PQP + s * 9 + h];
                fq0c[js] = (float)fq2.x; fq1c[js] = (float)fq2.y;
                pq0[js] = (float)pq2.x;  pq1[js] = (float)pq2.y;
            }
            float ao00 = 0.f, ao01 = 0.f, ao10 = 0.f, ao11 = 0.f;
            #pragma unroll
            for (int ch = 0; ch < 2; ++ch) {
                float fk0[4], fk1[4], pk0[4], pk1[4], fv0[4], fv1[4], un[4];
                #pragma unroll
                for (int j = 0; j < 4; ++j) {
                    int t = 8 * g3 + ch * 4 + j;
                    h2f fk2 = *(const h2f*)&sm[FKP + t * 9 + h];
                    h2f pk2 = *(const h2f*)&sm[PKP + t * 9 + h];
                    h2f fv2 = *(const h2f*)&sm[FVP + t * 9 + h];
                    fk0[j] = (float)fk2.x; fk1[j] = (float)fk2.y;
                    pk0[j] = (float)pk2.x; pk1[j] = (float)pk2.y;
                    fv0[j] = (float)fv2.x; fv1[j] = (float)fv2.y;
                    un[j] = mu0 * fk0[j] + mu1 * fk1[j];
                }
                #pragma unroll
                for (int js = 0; js < 2; ++js) {
                    #pragma unroll
                    for (int j = 0; j < 4; ++j) {
                        float lp = pq0[js] * pk0[j] + pq1[js] * pk1[j];
                        float a1 = fq0c[js] * fk0[j] + fq1c[js] * fk1[j] + lp;
                        float a2 = un[j] + lp;
                        float w = tanh_scaled(a1) + tanh_scaled(a2);
                        if (js == 0) { ao00 += w * fv0[j]; ao01 += w * fv1[j]; }
                        else         { ao10 += w * fv0[j]; ao11 += w * fv1[j]; }
                    }
                }
            }
            #pragma unroll
            for (int off = 1; off <= 4; off <<= 1) {
                ao00 += __shfl_xor(ao00, off);
                ao01 += __shfl_xor(ao01, off);
                ao10 += __shfl_xor(ao10, off);
                ao11 += __shfl_xor(ao11, off);
            }
            if (g3 == 0) {
                sm[AO + (2 * m3) * 20 + 2 * h]         = ao00;
                sm[AO + (2 * m3) * 20 + 2 * h + 1]     = ao01;
                sm[AO + (2 * m3 + 1) * 20 + 2 * h]     = ao10;
                sm[AO + (2 * m3 + 1) * 20 + 2 * h + 1] = ao11;
            }
        }
        __syncthreads();

        // phase 4
        const int t = tid & 63, oq = tid >> 6;
        float aorow[16];
        #pragma unroll
        for (int i = 0; i < 4; ++i)
            *(float4*)&aorow[i * 4] = *(const float4*)&sm[AO + t * 20 + i * 4];
        float* aop = aoc + (n * 25 + v) * 1024;
        #pragma unroll
        for (int j = 0; j < 4; ++j) {
            int o = oq * 4 + j;
            float acc4 = attn_b[o];
            #pragma unroll
            for (int c = 0; c < 16; ++c) acc4 += attn_w[o * 16 + c] * aorow[c];
            aop[o * 64 + t] = acc4;
            float ssum = acc4;
            #pragma unroll
            for (int off = 32; off >= 1; off >>= 1) ssum += __shfl_down(ssum, off, 64);
            if ((tid & 63) == 0) atomicAdd(&se[n * 64 + 48 + o], ssum);
        }
    }
}

// ---------------------------------------------------------------------------
// K3: gate. Computes conv-channel sums ANALYTICALLY (zero-pad edge correction
// from Tt), combines with attn se sums + x sums, runs the SE MLP.
// seL[c<48] = (a*convsum + 1600*cbias + S[c]) / 1600
// seL[c>=48] = (se_attn[c] + S[c]) / 1600
// ---------------------------------------------------------------------------
__global__ __launch_bounds__(64) void gate_kernel(
    const float* __restrict__ se, const float* __restrict__ Sbuf,
    const float* __restrict__ Tt, const ushort* __restrict__ wb,
    const float* __restrict__ tcn_b, const float* __restrict__ tg,
    const float* __restrict__ tb,
    const float* __restrict__ fc1w, const float* __restrict__ fc1b,
    const float* __restrict__ fc2w, const float* __restrict__ fc2b,
    float* __restrict__ gate)
{
    const int n = blockIdx.x;
    const int tid = threadIdx.x;
    __shared__ float U[64][9], seL[64], hid[32];
    const float rs = rsqrtf(1.f + 1e-5f);

    {   // U[ci][kt] = S - E(kt)
        int ci = tid;
        float S = Sbuf[n * 64 + ci];
        float T[8];
        #pragma unroll
        for (int j = 0; j < 8; ++j) T[j] = Tt[(n * 64 + ci) * 8 + j];
        U[ci][0] = S - (T[4] + T[5] + T[6] + T[7]);
        U[ci][1] = S - (T[5] + T[6] + T[7]);
        U[ci][2] = S - (T[6] + T[7]);
        U[ci][3] = S - T[7];
        U[ci][4] = S;
        U[ci][5] = S - T[0];
        U[ci][6] = S - (T[0] + T[1]);
        U[ci][7] = S - (T[0] + T[1] + T[2]);
        U[ci][8] = S - (T[0] + T[1] + T[2] + T[3]);
    }
    __syncthreads();

    if (tid < 48) {
        int oc = tid;
        float cs = 0.f;
        #pragma unroll 1
        for (int kt = 0; kt < 9; ++kt) {
            #pragma unroll
            for (int cb = 0; cb < 8; ++cb) {
                bf16x8 w8 = *(const bf16x8*)&wb[oc * 576 + kt * 64 + cb * 8];
                #pragma unroll
                for (int i = 0; i < 8; ++i)
                    cs += bf2f((ushort)w8[i]) * U[cb * 8 + i][kt];
            }
        }
        float a = tg[oc] * rs;
        float cb_ = tcn_b[oc] * a + tb[oc];
        seL[oc] = (a * cs + 1600.f * cb_ + Sbuf[n * 64 + oc]) * (1.f / 1600.f);
    } else {
        int c = tid + 0;   // 48..63
        seL[c] = (se[n * 64 + c] + Sbuf[n * 64 + c]) * (1.f / 1600.f);
    }
    __syncthreads();
    if (tid < 32) {
        float a = fc1b[tid];
        #pragma unroll
        for (int c = 0; c < 64; ++c) a += fc1w[tid * 64 + c] * seL[c];
        hid[tid] = fmaxf(a, 0.f);
    }
    __syncthreads();
    float g = fc2b[tid];
    #pragma unroll
    for (int j = 0; j < 32; ++j) g += fc2w[tid * 32 + j] * hid[j];
    gate[n * 64 + tid] = 1.f / (1.f + __expf(-g));
}

// ---------------------------------------------------------------------------
// K2: tcn MFMA. Epilogue applies gate+BN+ReLU directly (gate known) and
// writes FINAL output for c<48. No se atomics.
// ---------------------------------------------------------------------------
__global__ __launch_bounds__(512, 1) void tcn_mfma_kernel(
    const ushort* __restrict__ rt, const float* __restrict__ x,
    const ushort* __restrict__ wb,
    const float* __restrict__ tcn_b, const float* __restrict__ tg,
    const float* __restrict__ tb, const float* __restrict__ gate,
    const float* __restrict__ bng, const float* __restrict__ bnb,
    float* __restrict__ out)
{
    __shared__ ushort xsl[600 * 72];
    const int b = blockIdx.x;
    const int n = b >> 2, tile = b & 3;
    const int t0 = tile * 16;
    const int tid = threadIdx.x;

    const int tvbase = (t0 - 4) * 25;
    for (int idx = tid; idx < 4800; idx += 512) {
        int r = idx >> 3, part = idx & 7;
        int tv = tvbase + r;
        uint4 val = make_uint4(0u, 0u, 0u, 0u);
        if (tv >= 0 && tv < TV_) val = *(const uint4*)&rt[(n * TV_ + tv) * 64 + part * 8];
        *(uint4*)&xsl[r * 72 + part * 8] = val;
    }
    __syncthreads();

    const int lane = tid & 63, wave = tid >> 6;
    const int m16 = lane & 15, q = lane >> 4;
    const int nt0 = wave * 3;

    f32x4 acc[3][3];
    f32x4 acc24[3];
    #pragma unroll
    for (int i = 0; i < 3; ++i)
        #pragma unroll
        for (int mt = 0; mt < 3; ++mt)
            acc[i][mt] = (f32x4){0.f, 0.f, 0.f, 0.f};
    #pragma unroll
    for (int mt = 0; mt < 3; ++mt) acc24[mt] = (f32x4){0.f, 0.f, 0.f, 0.f};

    for (int ktile = 0; ktile < 18; ++ktile) {
        const int kt = ktile >> 1;
        const int cib = (ktile & 1) * 32 + q * 8;
        bf16x8 afr[3];
        #pragma unroll
        for (int mt = 0; mt < 3; ++mt)
            afr[mt] = *(const bf16x8*)&wb[(mt * 16 + m16) * 576 + ktile * 32 + q * 8];
        #pragma unroll
        for (int i = 0; i < 3; ++i) {
            int p = (nt0 + i) * 16 + m16;
            bf16x8 bfr = *(const bf16x8*)&xsl[(p + kt * 25) * 72 + cib];
            #pragma unroll
            for (int mt = 0; mt < 3; ++mt)
                acc[i][mt] = __builtin_amdgcn_mfma_f32_16x16x32_bf16(afr[mt], bfr, acc[i][mt], 0, 0, 0);
        }
        if (wave == 0) {
            int p = 24 * 16 + m16;
            bf16x8 bfr = *(const bf16x8*)&xsl[(p + kt * 25) * 72 + cib];
            #pragma unroll
            for (int mt = 0; mt < 3; ++mt)
                acc24[mt] = __builtin_amdgcn_mfma_f32_16x16x32_bf16(afr[mt], bfr, acc24[mt], 0, 0, 0);
        }
    }

    const float rsbn = rsqrtf(1.f + 1e-5f);
    float cb3[3][4], m3_[3][4], bb3[3][4];
    #pragma unroll
    for (int mt = 0; mt < 3; ++mt)
        #pragma unroll
        for (int r = 0; r < 4; ++r) {
            int oc = mt * 16 + q * 4 + r;
            float a = tg[oc] * rsbn;
            cb3[mt][r] = tcn_b[oc] * a + tb[oc];
            m3_[mt][r] = (1.f + gate[n * 64 + oc]) * (bng[oc] * rsbn);
            bb3[mt][r] = bnb[oc];
        }
    #pragma unroll
    for (int i = 0; i < 3; ++i) {
        int posg = tile * 400 + (nt0 + i) * 16 + m16;
        #pragma unroll
        for (int mt = 0; mt < 3; ++mt) {
            #pragma unroll
            for (int r = 0; r < 4; ++r) {
                int oc = mt * 16 + q * 4 + r;
                float val = acc[i][mt][r] + cb3[mt][r] + x[(n * 64 + oc) * TV_ + posg];
                out[(n * 64 + oc) * TV_ + posg] = fmaxf(val * m3_[mt][r] + bb3[mt][r], 0.f);
            }
        }
    }
    if (wave == 0) {
        int posg = tile * 400 + 24 * 16 + m16;
        #pragma unroll
        for (int mt = 0; mt < 3; ++mt) {
            #pragma unroll
            for (int r = 0; r < 4; ++r) {
                int oc = mt * 16 + q * 4 + r;
                float val = acc24[mt][r] + cb3[mt][r] + x[(n * 64 + oc) * TV_ + posg];
                out[(n * 64 + oc) * TV_ + posg] = fmaxf(val * m3_[mt][r] + bb3[mt][r], 0.f);
            }
        }
    }
}

// ---------------------------------------------------------------------------
// K4: final assembles ONLY c>=48 (quarter): aoc gather + x residual + gate +
// BN + relu. 409600 float4s -> 1600 blocks.
// ---------------------------------------------------------------------------
__global__ __launch_bounds__(256) void final_kernel(
    float* __restrict__ out, const float* __restrict__ aoc,
    const float* __restrict__ x, const float* __restrict__ gate,
    const float* __restrict__ bng, const float* __restrict__ bnb)
{
    const float rs = rsqrtf(1.f + 1e-5f);
    int idx = blockIdx.x * 256 + threadIdx.x;      // 0..409599
    int n = idx / 6400;
    int rem = idx - n * 6400;
    int o = rem / 400, r4 = rem - o * 400;

    float4 val;
    const float* ap = aoc + (n * 25) * 1024 + o * 64;
    #pragma unroll
    for (int e = 0; e < 4; ++e) {
        int pos = r4 * 4 + e;
        int t = pos / 25, v = pos - t * 25;
        ((float*)&val)[e] = ap[v * 1024 + t];
    }
    int g4 = (n * 64 + 48 + o) * 400 + r4;
    float4 xr = ((const float4*)x)[g4];
    float mm = (1.f + gate[n * 64 + 48 + o]) * (bng[48 + o] * rs);
    float bb = bnb[48 + o];
    val.x = fmaxf((val.x + xr.x) * mm + bb, 0.f);
    val.y = fmaxf((val.y + xr.y) * mm + bb, 0.f);
    val.z = fmaxf((val.z + xr.z) * mm + bb, 0.f);
    val.w = fmaxf((val.w + xr.w) * mm + bb, 0.f);
    ((float4*)out)[g4] = val;
}

extern "C" void kernel_launch(void* const* d_in, const int* in_sizes, int n_in,
                              void* d_out, int out_size, void* d_ws, size_t ws_size,
                              hipStream_t stream) {
    const float* x     = (const float*)d_in[0];
    const float* pe    = (const float*)d_in[1];
    const float* dbg   = (const float*)d_in[2];
    const float* dbb   = (const float*)d_in[3];
    const float* qkvw  = (const float*)d_in[4];
    const float* qkvb  = (const float*)d_in[5];
    const float* attnw = (const float*)d_in[6];
    const float* attnb = (const float*)d_in[7];
    const float* tcnw  = (const float*)d_in[8];
    const float* tcnb  = (const float*)d_in[9];
    const float* tcng  = (const float*)d_in[10];
    const float* tcnbb = (const float*)d_in[11];
    const float* fc1w  = (const float*)d_in[12];
    const float* fc1b  = (const float*)d_in[13];
    const float* fc2w  = (const float*)d_in[14];
    const float* fc2b  = (const float*)d_in[15];
    const float* bng   = (const float*)d_in[16];
    const float* bnb   = (const float*)d_in[17];

    float* out  = (float*)d_out;
    float* se   = (float*)d_ws;                      // 4096 f
    float* Sbuf = se + 4096;                         // 4096 f
    float* Tt   = Sbuf + 4096;                       // 32768 f
    float* gate = Tt + 32768;                        // 4096 f
    float* qb   = gate + 4096;                       // 96 f
    float* aoc  = qb + 96;                           // 1,638,400 f
    ushort* wb  = (ushort*)(aoc + 1638400);          // 27648 u16
    ushort* wq  = wb + 27648;                        // 5120 u16
    ushort* pet = wq + 5120;                         // 102,400 u16
    ushort* rt  = pet + 102400;                      // 6,553,600 u16

    hipMemsetAsync(se, 0, (4096 + 4096) * sizeof(float), stream);   // se + Sbuf
    t1_kernel<<<dim3(27, 64), dim3(256), 0, stream>>>(
        x, pe, tcnw, tcng, qkvw, qkvb, rt, Sbuf, Tt, wb, wq, qb, pet);
    score_kernel<<<dim3(800), dim3(256), 0, stream>>>(rt, pet, dbg, dbb, wq, qb, attnw, attnb, aoc, se);
    gate_kernel<<<dim3(64), dim3(64), 0, stream>>>(
        se, Sbuf, Tt, wb, tcnb, tcng, tcnbb, fc1w, fc1b, fc2w, fc2b, gate);
    tcn_mfma_kernel<<<dim3(256), dim3(512), 0, stream>>>(
        rt, x, wb, tcnb, tcng, tcnbb, gate, bng, bnb, out);
    final_kernel<<<dim3(1600), dim3(256), 0, stream>>>(out, aoc, x, gate, bng, bnb);
}

// Round 13
// 226.033 us; speedup vs baseline: 1.2313x; 1.2313x over previous
//
#include <hip/hip_runtime.h>
#include <hip/hip_bf16.h>
#include <math.h>

#define TV_ 1600
#define SCALE_K 2.885390081777927f   // 2*log2(e): folded into fk/pk rows so tanh uses exp2 directly
#define RS2_ 0.70710678118654752f    // DKH^-0.5 folded into fq/pq rows

typedef __attribute__((ext_vector_type(8))) short bf16x8;
typedef __attribute__((ext_vector_type(4))) float f32x4;
typedef __attribute__((ext_vector_type(2))) __fp16 h2f;

__device__ __forceinline__ float tanh_scaled(float y) {
    y = fminf(44.f, fmaxf(-44.f, y));
    float e = __builtin_amdgcn_exp2f(y);
    float r = __builtin_amdgcn_rcpf(e + 1.f);
    return __builtin_fmaf(e, r, -r);
}

__device__ __forceinline__ ushort f2bf(float f) {
    __hip_bfloat16 h = __float2bfloat16(f);
    return *(ushort*)&h;
}
__device__ __forceinline__ float bf2f(ushort u) {
    uint w = ((uint)u) << 16;
    return __uint_as_float(w);
}

// ---------------------------------------------------------------------------
// T1 (fused): bx<25: transpose slice -> rt[n][tv][ci]=bf16(x) + Sbuf atomics.
// bx==25: prep (wb/wq/qb/pet). bx==26: edge t-slice sums Tt.
// ---------------------------------------------------------------------------
__global__ __launch_bounds__(256) void t1_kernel(
    const float* __restrict__ x, const float* __restrict__ pe,
    const float* __restrict__ tcn_w, const float* __restrict__ tg,
    const float* __restrict__ qkv_w, const float* __restrict__ qkv_b,
    ushort* __restrict__ rt, float* __restrict__ Sbuf, float* __restrict__ Tt,
    ushort* __restrict__ wb, ushort* __restrict__ wq, float* __restrict__ qb,
    ushort* __restrict__ pet)
{
    const int tid = threadIdx.x;
    const int bx = blockIdx.x, by = blockIdx.y;

    if (bx == 25) {   // prep slice
        #pragma unroll 1
        for (int j = 0; j < 9; ++j) {
            int idx = by * 256 + tid + j * 16384;
            if (idx < 27648) {
                int oc = idx / 576, kk = idx - oc * 576;
                int kt = kk >> 6, ci = kk & 63;
                float a = tg[oc] * rsqrtf(1.f + 1e-5f);
                wb[idx] = f2bf(tcn_w[(oc * 64 + ci) * 9 + kt] * a);
            } else if (idx < 32768) {
                int i2 = idx - 27648;
                int r = i2 >> 6, c = i2 & 63;
                int src; float sc;
                if (r < 16)      { src = r;      sc = RS2_; }
                else if (r < 32) { src = r;      sc = SCALE_K; }
                else if (r < 48) { src = r + 16; sc = 1.f; }
                else if (r < 64) { src = r - 48; sc = RS2_; }
                else             { src = r - 48; sc = SCALE_K; }
                wq[i2] = f2bf(qkv_w[src * 64 + c] * sc);
            } else if (idx < 32848) {
                int r = idx - 32768;
                int src; float sc;
                if (r < 16)      { src = r;      sc = RS2_; }
                else if (r < 32) { src = r;      sc = SCALE_K; }
                else if (r < 48) { src = r + 16; sc = 1.f; }
                else if (r < 64) { src = r - 48; sc = RS2_; }
                else             { src = r - 48; sc = SCALE_K; }
                qb[r] = qkv_b[src] * sc;
            } else if (idx < 135248) {
                int i3 = idx - 32848;
                int ci = i3 / 1600, tv = i3 - ci * 1600;
                pet[tv * 64 + ci] = f2bf(pe[ci * 1600 + tv]);
            }
        }
        return;
    }
    if (bx == 26) {   // edge t-slice sums: slot 0..3 -> t=slot; slot 4..7 -> t=56+slot
        const int n = by;
        #pragma unroll
        for (int it = 0; it < 2; ++it) {
            int item = tid + it * 256;
            int ci = item >> 3, slot = item & 7;
            int t = (slot < 4) ? slot : (56 + slot);
            const float* xp = x + (n * 64 + ci) * TV_ + t * 25;
            float s = 0.f;
            #pragma unroll
            for (int v = 0; v < 25; ++v) s += xp[v];
            Tt[(n * 64 + ci) * 8 + slot] = s;
        }
        return;
    }

    // transpose slice
    __shared__ ushort smt[64 * 66];
    const int tv0 = bx * 64;
    const int n = by;
    const int tvl = tid & 63, cig = tid >> 6;
    const int tv = tv0 + tvl;

    float psum[16];
    #pragma unroll
    for (int k = 0; k < 16; ++k) psum[k] = 0.f;
    #pragma unroll
    for (int k = 0; k < 16; ++k) {
        int ci = k * 4 + cig;
        float xv = x[(n * 64 + ci) * TV_ + tv];
        smt[tvl * 66 + ci] = f2bf(xv);
        psum[k] += xv;
    }
    #pragma unroll
    for (int k = 0; k < 16; ++k) {
        float s = psum[k];
        #pragma unroll
        for (int off = 32; off >= 1; off >>= 1) s += __shfl_down(s, off, 64);
        if (tvl == 0) atomicAdd(&Sbuf[n * 64 + k * 4 + cig], s);
    }
    __syncthreads();

    #pragma unroll
    for (int j = 0; j < 8; ++j) {
        int chunk = tid + j * 256;
        int tvr = chunk >> 5, p = chunk & 31;
        uint val = *(const uint*)&smt[tvr * 66 + p * 2];
        *(uint*)&rt[(n * TV_ + tv0 + tvr) * 64 + p * 2] = val;
    }
}

// ---------------------------------------------------------------------------
// K1: score kernel per (n,v) — VERBATIM round 11 (62 us, FETCH 7.4 MB
// measured). Grid 1600, b>>3 XCD swizzle, one (n,v) per block.
// ---------------------------------------------------------------------------
__global__ __launch_bounds__(256, 5) void score_kernel(
    const ushort* __restrict__ rt, const ushort* __restrict__ pet,
    const float* __restrict__ dbg, const float* __restrict__ dbb,
    const ushort* __restrict__ wq, const float* __restrict__ qb,
    const float* __restrict__ attn_w, const float* __restrict__ attn_b,
    float* __restrict__ aoc, float* __restrict__ se)
{
    __shared__ float sm[5312];
    ushort* smu = (ushort*)sm;
    const int MU_ = 1056, AO = 1120;
    const int FKP = 2400, PKP = 2976, FVP = 3552, PQP = 4128, FQP = 4704;

    const int b = blockIdx.x;
    const int l = b >> 3;
    const int n = (b & 7) * 8 + l / 25;
    const int v = l % 25;
    const int tid = threadIdx.x;

    const int lane = tid & 63, wave = tid >> 6;
    const int m16 = lane & 15, q = lane >> 4;

    // phase 1: build xn/yb bf16 planes from rt + pet
    {
        const int part = tid & 7;
        const int ci0 = part * 8;
        const float rs = rsqrtf(1.f + 1e-5f);
        float sc8[8], sh8[8];
        #pragma unroll
        for (int i = 0; i < 8; ++i) {
            sc8[i] = dbg[(ci0 + i) * 25 + v] * rs;
            sh8[i] = dbb[(ci0 + i) * 25 + v];
        }
        #pragma unroll
        for (int j = 0; j < 2; ++j) {
            int t = (tid + j * 256) >> 3;
            uint4 xr = *(const uint4*)&rt[(n * TV_ + t * 25 + v) * 64 + ci0];
            uint4 pr = *(const uint4*)&pet[(t * 25 + v) * 64 + ci0];
            const ushort* xu = (const ushort*)&xr;
            const ushort* pu = (const ushort*)&pr;
            ushort xs[8], ys[8];
            #pragma unroll
            for (int i = 0; i < 8; ++i) {
                float xf = bf2f(xu[i]);
                xs[i] = f2bf(xf * sc8[i] + sh8[i]);
                ys[i] = f2bf(xf + bf2f(pu[i]));
            }
            *(uint4*)&smu[t * 72 + ci0] = *(uint4*)xs;
            *(uint4*)&smu[4608 + t * 72 + ci0] = *(uint4*)ys;
        }
    }
    __syncthreads();

    // phase 2: qkv MFMA
    f32x4 acc[5];
    #pragma unroll
    for (int mt = 0; mt < 5; ++mt) acc[mt] = (f32x4){0.f, 0.f, 0.f, 0.f};
    #pragma unroll
    for (int kt = 0; kt < 2; ++kt) {
        const int koff = kt * 32 + q * 8;
        bf16x8 bx = *(const bf16x8*)&smu[(wave * 16 + m16) * 72 + koff];
        bf16x8 by = *(const bf16x8*)&smu[4608 + (wave * 16 + m16) * 72 + koff];
        #pragma unroll
        for (int mt = 0; mt < 5; ++mt) {
            bf16x8 a = *(const bf16x8*)&wq[(mt * 16 + m16) * 64 + koff];
            acc[mt] = __builtin_amdgcn_mfma_f32_16x16x32_bf16(a, (mt < 3) ? bx : by, acc[mt], 0, 0, 0);
        }
    }
    __syncthreads();

    // phase 2b
    {
        const int t = wave * 16 + m16;
        #pragma unroll
        for (int r = 0; r < 4; ++r)
            sm[(q * 4 + r) * 66 + t] = acc[0][r] + qb[q * 4 + r];
        *(h2f*)&sm[FKP + t * 9 + 2 * q] =
            __builtin_amdgcn_cvt_pkrtz(acc[1][0] + qb[16 + q * 4], acc[1][1] + qb[16 + q * 4 + 1]);
        *(h2f*)&sm[FKP + t * 9 + 2 * q + 1] =
            __builtin_amdgcn_cvt_pkrtz(acc[1][2] + qb[16 + q * 4 + 2], acc[1][3] + qb[16 + q * 4 + 3]);
        *(h2f*)&sm[FVP + t * 9 + 2 * q] =
            __builtin_amdgcn_cvt_pkrtz(acc[2][0] + qb[32 + q * 4], acc[2][1] + qb[32 + q * 4 + 1]);
        *(h2f*)&sm[FVP + t * 9 + 2 * q + 1] =
            __builtin_amdgcn_cvt_pkrtz(acc[2][2] + qb[32 + q * 4 + 2], acc[2][3] + qb[32 + q * 4 + 3]);
        *(h2f*)&sm[PQP + t * 9 + 2 * q] =
            __builtin_amdgcn_cvt_pkrtz(acc[3][0] + qb[48 + q * 4], acc[3][1] + qb[48 + q * 4 + 1]);
        *(h2f*)&sm[PQP + t * 9 + 2 * q + 1] =
            __builtin_amdgcn_cvt_pkrtz(acc[3][2] + qb[48 + q * 4 + 2], acc[3][3] + qb[48 + q * 4 + 3]);
        *(h2f*)&sm[PKP + t * 9 + 2 * q] =
            __builtin_amdgcn_cvt_pkrtz(acc[4][0] + qb[64 + q * 4], acc[4][1] + qb[64 + q * 4 + 1]);
        *(h2f*)&sm[PKP + t * 9 + 2 * q + 1] =
            __builtin_amdgcn_cvt_pkrtz(acc[4][2] + qb[64 + q * 4 + 2], acc[4][3] + qb[64 + q * 4 + 3]);
    }
    __syncthreads();

    // mu
    if (tid < 64) {
        int ch = tid & 15, qq = tid >> 4;
        float s = 0.f;
        #pragma unroll
        for (int t = 0; t < 16; ++t) s += sm[ch * 66 + qq * 16 + t];
        sm[MU_ + qq * 16 + ch] = s;
    }
    __syncthreads();
    if (tid < 16) {
        float mval = (sm[MU_ + tid] + sm[MU_ + 16 + tid] + sm[MU_ + 32 + tid] + sm[MU_ + 48 + tid]) * (1.f / 64.f);
        sm[MU_ + tid] = mval;
    }
    __syncthreads();

    // fqc pack
    #pragma unroll
    for (int e = 0; e < 2; ++e) {
        int idx = tid * 2 + e;
        int s = idx >> 3, h = idx & 7;
        float a = sm[(2 * h) * 66 + s] - sm[MU_ + 2 * h];
        float c = sm[(2 * h + 1) * 66 + s] - sm[MU_ + 2 * h + 1];
        *(h2f*)&sm[FQP + s * 9 + h] = __builtin_amdgcn_cvt_pkrtz(a, c);
    }
    __syncthreads();

    // phase 3
    const int g3 = tid & 7, m3 = tid >> 3;
    #pragma unroll 1
    for (int h = 0; h < 8; ++h) {
        const float mu0 = sm[MU_ + 2 * h], mu1 = sm[MU_ + 2 * h + 1];
        float fq0c[2], fq1c[2], pq0[2], pq1[2];
        #pragma unroll
        for (int js = 0; js < 2; ++js) {
            int s = 2 * m3 + js;
            h2f fq2 = *(const h2f*)&sm[FQP + s * 9 + h];
            h2f pq2 = *(const h2f*)&sm[PQP + s * 9 + h];
            fq0c[js] = (float)fq2.x; fq1c[js] = (float)fq2.y;
            pq0[js] = (float)pq2.x;  pq1[js] = (float)pq2.y;
        }
        float ao00 = 0.f, ao01 = 0.f, ao10 = 0.f, ao11 = 0.f;
        #pragma unroll
        for (int ch = 0; ch < 2; ++ch) {
            float fk0[4], fk1[4], pk0[4], pk1[4], fv0[4], fv1[4], un[4];
            #pragma unroll
            for (int j = 0; j < 4; ++j) {
                int t = 8 * g3 + ch * 4 + j;
                h2f fk2 = *(const h2f*)&sm[FKP + t * 9 + h];
                h2f pk2 = *(const h2f*)&sm[PKP + t * 9 + h];
                h2f fv2 = *(const h2f*)&sm[FVP + t * 9 + h];
                fk0[j] = (float)fk2.x; fk1[j] = (float)fk2.y;
                pk0[j] = (float)pk2.x; pk1[j] = (float)pk2.y;
                fv0[j] = (float)fv2.x; fv1[j] = (float)fv2.y;
                un[j] = mu0 * fk0[j] + mu1 * fk1[j];
            }
            #pragma unroll
            for (int js = 0; js < 2; ++js) {
                #pragma unroll
                for (int j = 0; j < 4; ++j) {
                    float lp = pq0[js] * pk0[j] + pq1[js] * pk1[j];
                    float a1 = fq0c[js] * fk0[j] + fq1c[js] * fk1[j] + lp;
                    float a2 = un[j] + lp;
                    float w = tanh_scaled(a1) + tanh_scaled(a2);
                    if (js == 0) { ao00 += w * fv0[j]; ao01 += w * fv1[j]; }
                    else         { ao10 += w * fv0[j]; ao11 += w * fv1[j]; }
                }
            }
        }
        #pragma unroll
        for (int off = 1; off <= 4; off <<= 1) {
            ao00 += __shfl_xor(ao00, off);
            ao01 += __shfl_xor(ao01, off);
            ao10 += __shfl_xor(ao10, off);
            ao11 += __shfl_xor(ao11, off);
        }
        if (g3 == 0) {
            sm[AO + (2 * m3) * 20 + 2 * h]         = ao00;
            sm[AO + (2 * m3) * 20 + 2 * h + 1]     = ao01;
            sm[AO + (2 * m3 + 1) * 20 + 2 * h]     = ao10;
            sm[AO + (2 * m3 + 1) * 20 + 2 * h + 1] = ao11;
        }
    }
    __syncthreads();

    // phase 4
    const int t = tid & 63, oq = tid >> 6;
    float aorow[16];
    #pragma unroll
    for (int i = 0; i < 4; ++i)
        *(float4*)&aorow[i * 4] = *(const float4*)&sm[AO + t * 20 + i * 4];
    float* aop = aoc + (n * 25 + v) * 1024;
    #pragma unroll
    for (int j = 0; j < 4; ++j) {
        int o = oq * 4 + j;
        float acc4 = attn_b[o];
        #pragma unroll
        for (int c = 0; c < 16; ++c) acc4 += attn_w[o * 16 + c] * aorow[c];
        aop[o * 64 + t] = acc4;
        float ssum = acc4;
        #pragma unroll
        for (int off = 32; off >= 1; off >>= 1) ssum += __shfl_down(ssum, off, 64);
        if ((tid & 63) == 0) atomicAdd(&se[n * 64 + 48 + o], ssum);
    }
}

// ---------------------------------------------------------------------------
// K3: gate — analytic conv-channel sums (zero-pad correction via Tt) + attn
// se + x sums -> SE MLP.
// ---------------------------------------------------------------------------
__global__ __launch_bounds__(64) void gate_kernel(
    const float* __restrict__ se, const float* __restrict__ Sbuf,
    const float* __restrict__ Tt, const ushort* __restrict__ wb,
    const float* __restrict__ tcn_b, const float* __restrict__ tg,
    const float* __restrict__ tb,
    const float* __restrict__ fc1w, const float* __restrict__ fc1b,
    const float* __restrict__ fc2w, const float* __restrict__ fc2b,
    float* __restrict__ gate)
{
    const int n = blockIdx.x;
    const int tid = threadIdx.x;
    __shared__ float U[64][9], seL[64], hid[32];
    const float rs = rsqrtf(1.f + 1e-5f);

    {
        int ci = tid;
        float S = Sbuf[n * 64 + ci];
        float T[8];
        #pragma unroll
        for (int j = 0; j < 8; ++j) T[j] = Tt[(n * 64 + ci) * 8 + j];
        U[ci][0] = S - (T[4] + T[5] + T[6] + T[7]);
        U[ci][1] = S - (T[5] + T[6] + T[7]);
        U[ci][2] = S - (T[6] + T[7]);
        U[ci][3] = S - T[7];
        U[ci][4] = S;
        U[ci][5] = S - T[0];
        U[ci][6] = S - (T[0] + T[1]);
        U[ci][7] = S - (T[0] + T[1] + T[2]);
        U[ci][8] = S - (T[0] + T[1] + T[2] + T[3]);
    }
    __syncthreads();

    if (tid < 48) {
        int oc = tid;
        float cs = 0.f;
        #pragma unroll 1
        for (int kt = 0; kt < 9; ++kt) {
            #pragma unroll
            for (int cb = 0; cb < 8; ++cb) {
                bf16x8 w8 = *(const bf16x8*)&wb[oc * 576 + kt * 64 + cb * 8];
                #pragma unroll
                for (int i = 0; i < 8; ++i)
                    cs += bf2f((ushort)w8[i]) * U[cb * 8 + i][kt];
            }
        }
        float a = tg[oc] * rs;
        float cb_ = tcn_b[oc] * a + tb[oc];
        seL[oc] = (a * cs + 1600.f * cb_ + Sbuf[n * 64 + oc]) * (1.f / 1600.f);
    } else {
        seL[tid] = (se[n * 64 + tid] + Sbuf[n * 64 + tid]) * (1.f / 1600.f);
    }
    __syncthreads();
    if (tid < 32) {
        float a = fc1b[tid];
        #pragma unroll
        for (int c = 0; c < 64; ++c) a += fc1w[tid * 64 + c] * seL[c];
        hid[tid] = fmaxf(a, 0.f);
    }
    __syncthreads();
    float g = fc2b[tid];
    #pragma unroll
    for (int j = 0; j < 32; ++j) g += fc2w[tid * 32 + j] * hid[j];
    gate[n * 64 + tid] = 1.f / (1.f + __expf(-g));
}

// ---------------------------------------------------------------------------
// K2: tcn MFMA; epilogue applies gate+BN+ReLU and writes FINAL c<48.
// ---------------------------------------------------------------------------
__global__ __launch_bounds__(512, 1) void tcn_mfma_kernel(
    const ushort* __restrict__ rt, const float* __restrict__ x,
    const ushort* __restrict__ wb,
    const float* __restrict__ tcn_b, const float* __restrict__ tg,
    const float* __restrict__ tb, const float* __restrict__ gate,
    const float* __restrict__ bng, const float* __restrict__ bnb,
    float* __restrict__ out)
{
    __shared__ ushort xsl[600 * 72];
    const int b = blockIdx.x;
    const int n = b >> 2, tile = b & 3;
    const int t0 = tile * 16;
    const int tid = threadIdx.x;

    const int tvbase = (t0 - 4) * 25;
    for (int idx = tid; idx < 4800; idx += 512) {
        int r = idx >> 3, part = idx & 7;
        int tv = tvbase + r;
        uint4 val = make_uint4(0u, 0u, 0u, 0u);
        if (tv >= 0 && tv < TV_) val = *(const uint4*)&rt[(n * TV_ + tv) * 64 + part * 8];
        *(uint4*)&xsl[r * 72 + part * 8] = val;
    }
    __syncthreads();

    const int lane = tid & 63, wave = tid >> 6;
    const int m16 = lane & 15, q = lane >> 4;
    const int nt0 = wave * 3;

    f32x4 acc[3][3];
    f32x4 acc24[3];
    #pragma unroll
    for (int i = 0; i < 3; ++i)
        #pragma unroll
        for (int mt = 0; mt < 3; ++mt)
            acc[i][mt] = (f32x4){0.f, 0.f, 0.f, 0.f};
    #pragma unroll
    for (int mt = 0; mt < 3; ++mt) acc24[mt] = (f32x4){0.f, 0.f, 0.f, 0.f};

    for (int ktile = 0; ktile < 18; ++ktile) {
        const int kt = ktile >> 1;
        const int cib = (ktile & 1) * 32 + q * 8;
        bf16x8 afr[3];
        #pragma unroll
        for (int mt = 0; mt < 3; ++mt)
            afr[mt] = *(const bf16x8*)&wb[(mt * 16 + m16) * 576 + ktile * 32 + q * 8];
        #pragma unroll
        for (int i = 0; i < 3; ++i) {
            int p = (nt0 + i) * 16 + m16;
            bf16x8 bfr = *(const bf16x8*)&xsl[(p + kt * 25) * 72 + cib];
            #pragma unroll
            for (int mt = 0; mt < 3; ++mt)
                acc[i][mt] = __builtin_amdgcn_mfma_f32_16x16x32_bf16(afr[mt], bfr, acc[i][mt], 0, 0, 0);
        }
        if (wave == 0) {
            int p = 24 * 16 + m16;
            bf16x8 bfr = *(const bf16x8*)&xsl[(p + kt * 25) * 72 + cib];
            #pragma unroll
            for (int mt = 0; mt < 3; ++mt)
                acc24[mt] = __builtin_amdgcn_mfma_f32_16x16x32_bf16(afr[mt], bfr, acc24[mt], 0, 0, 0);
        }
    }

    const float rsbn = rsqrtf(1.f + 1e-5f);
    float cb3[3][4], m3_[3][4], bb3[3][4];
    #pragma unroll
    for (int mt = 0; mt < 3; ++mt)
        #pragma unroll
        for (int r = 0; r < 4; ++r) {
            int oc = mt * 16 + q * 4 + r;
            float a = tg[oc] * rsbn;
            cb3[mt][r] = tcn_b[oc] * a + tb[oc];
            m3_[mt][r] = (1.f + gate[n * 64 + oc]) * (bng[oc] * rsbn);
            bb3[mt][r] = bnb[oc];
        }
    #pragma unroll
    for (int i = 0; i < 3; ++i) {
        int posg = tile * 400 + (nt0 + i) * 16 + m16;
        #pragma unroll
        for (int mt = 0; mt < 3; ++mt) {
            #pragma unroll
            for (int r = 0; r < 4; ++r) {
                int oc = mt * 16 + q * 4 + r;
                float val = acc[i][mt][r] + cb3[mt][r] + x[(n * 64 + oc) * TV_ + posg];
                out[(n * 64 + oc) * TV_ + posg] = fmaxf(val * m3_[mt][r] + bb3[mt][r], 0.f);
            }
        }
    }
    if (wave == 0) {
        int posg = tile * 400 + 24 * 16 + m16;
        #pragma unroll
        for (int mt = 0; mt < 3; ++mt) {
            #pragma unroll
            for (int r = 0; r < 4; ++r) {
                int oc = mt * 16 + q * 4 + r;
                float val = acc24[mt][r] + cb3[mt][r] + x[(n * 64 + oc) * TV_ + posg];
                out[(n * 64 + oc) * TV_ + posg] = fmaxf(val * m3_[mt][r] + bb3[mt][r], 0.f);
            }
        }
    }
}

// ---------------------------------------------------------------------------
// K4: final assembles ONLY c>=48: aoc gather + x residual + gate + BN + relu.
// ---------------------------------------------------------------------------
__global__ __launch_bounds__(256) void final_kernel(
    float* __restrict__ out, const float* __restrict__ aoc,
    const float* __restrict__ x, const float* __restrict__ gate,
    const float* __restrict__ bng, const float* __restrict__ bnb)
{
    const float rs = rsqrtf(1.f + 1e-5f);
    int idx = blockIdx.x * 256 + threadIdx.x;
    int n = idx / 6400;
    int rem = idx - n * 6400;
    int o = rem / 400, r4 = rem - o * 400;

    float4 val;
    const float* ap = aoc + (n * 25) * 1024 + o * 64;
    #pragma unroll
    for (int e = 0; e < 4; ++e) {
        int pos = r4 * 4 + e;
        int t = pos / 25, v = pos - t * 25;
        ((float*)&val)[e] = ap[v * 1024 + t];
    }
    int g4 = (n * 64 + 48 + o) * 400 + r4;
    float4 xr = ((const float4*)x)[g4];
    float mm = (1.f + gate[n * 64 + 48 + o]) * (bng[48 + o] * rs);
    float bb = bnb[48 + o];
    val.x = fmaxf((val.x + xr.x) * mm + bb, 0.f);
    val.y = fmaxf((val.y + xr.y) * mm + bb, 0.f);
    val.z = fmaxf((val.z + xr.z) * mm + bb, 0.f);
    val.w = fmaxf((val.w + xr.w) * mm + bb, 0.f);
    ((float4*)out)[g4] = val;
}

extern "C" void kernel_launch(void* const* d_in, const int* in_sizes, int n_in,
                              void* d_out, int out_size, void* d_ws, size_t ws_size,
                              hipStream_t stream) {
    const float* x     = (const float*)d_in[0];
    const float* pe    = (const float*)d_in[1];
    const float* dbg   = (const float*)d_in[2];
    const float* dbb   = (const float*)d_in[3];
    const float* qkvw  = (const float*)d_in[4];
    const float* qkvb  = (const float*)d_in[5];
    const float* attnw = (const float*)d_in[6];
    const float* attnb = (const float*)d_in[7];
    const float* tcnw  = (const float*)d_in[8];
    const float* tcnb  = (const float*)d_in[9];
    const float* tcng  = (const float*)d_in[10];
    const float* tcnbb = (const float*)d_in[11];
    const float* fc1w  = (const float*)d_in[12];
    const float* fc1b  = (const float*)d_in[13];
    const float* fc2w  = (const float*)d_in[14];
    const float* fc2b  = (const float*)d_in[15];
    const float* bng   = (const float*)d_in[16];
    const float* bnb   = (const float*)d_in[17];

    float* out  = (float*)d_out;
    float* se   = (float*)d_ws;                      // 4096 f
    float* Sbuf = se + 4096;                         // 4096 f
    float* Tt   = Sbuf + 4096;                       // 32768 f
    float* gate = Tt + 32768;                        // 4096 f
    float* qb   = gate + 4096;                       // 96 f
    float* aoc  = qb + 96;                           // 1,638,400 f
    ushort* wb  = (ushort*)(aoc + 1638400);          // 27648 u16
    ushort* wq  = wb + 27648;                        // 5120 u16
    ushort* pet = wq + 5120;                         // 102,400 u16
    ushort* rt  = pet + 102400;                      // 6,553,600 u16

    hipMemsetAsync(se, 0, (4096 + 4096) * sizeof(float), stream);
    t1_kernel<<<dim3(27, 64), dim3(256), 0, stream>>>(
        x, pe, tcnw, tcng, qkvw, qkvb, rt, Sbuf, Tt, wb, wq, qb, pet);
    score_kernel<<<dim3(1600), dim3(256), 0, stream>>>(rt, pet, dbg, dbb, wq, qb, attnw, attnb, aoc, se);
    gate_kernel<<<dim3(64), dim3(64), 0, stream>>>(
        se, Sbuf, Tt, wb, tcnb, tcng, tcnbb, fc1w, fc1b, fc2w, fc2b, gate);
    tcn_mfma_kernel<<<dim3(256), dim3(512), 0, stream>>>(
        rt, x, wb, tcnb, tcng, tcnbb, gate, bng, bnb, out);
    final_kernel<<<dim3(1600), dim3(256), 0, stream>>>(out, aoc, x, gate, bng, bnb);
}

// Round 14
// 220.009 us; speedup vs baseline: 1.2650x; 1.0274x over previous
//
#include <hip/hip_runtime.h>
#include <hip/hip_bf16.h>
#include <math.h>

#define TV_ 1600
#define SCALE_K 2.885390081777927f
#define RS2_ 0.70710678118654752f

typedef __attribute__((ext_vector_type(8))) short bf16x8;
typedef __attribute__((ext_vector_type(4))) float f32x4;
typedef __attribute__((ext_vector_type(2))) __fp16 h2f;

__device__ __forceinline__ float tanh_scaled(float y) {
    y = fminf(44.f, fmaxf(-44.f, y));
    float e = __builtin_amdgcn_exp2f(y);
    float r = __builtin_amdgcn_rcpf(e + 1.f);
    return __builtin_fmaf(e, r, -r);
}

__device__ __forceinline__ ushort f2bf(float f) {
    __hip_bfloat16 h = __float2bfloat16(f);
    return *(ushort*)&h;
}
__device__ __forceinline__ float bf2f(ushort u) {
    uint w = ((uint)u) << 16;
    return __uint_as_float(w);
}

// ---------------------------------------------------------------------------
// T1 (fused): bx<25 transpose -> rt + Sbuf; bx==25 prep; bx==26 edge sums Tt.
// (verbatim round 13)
// ---------------------------------------------------------------------------
__global__ __launch_bounds__(256) void t1_kernel(
    const float* __restrict__ x, const float* __restrict__ pe,
    const float* __restrict__ tcn_w, const float* __restrict__ tg,
    const float* __restrict__ qkv_w, const float* __restrict__ qkv_b,
    ushort* __restrict__ rt, float* __restrict__ Sbuf, float* __restrict__ Tt,
    ushort* __restrict__ wb, ushort* __restrict__ wq, float* __restrict__ qb,
    ushort* __restrict__ pet)
{
    const int tid = threadIdx.x;
    const int bx = blockIdx.x, by = blockIdx.y;

    if (bx == 25) {
        #pragma unroll 1
        for (int j = 0; j < 9; ++j) {
            int idx = by * 256 + tid + j * 16384;
            if (idx < 27648) {
                int oc = idx / 576, kk = idx - oc * 576;
                int kt = kk >> 6, ci = kk & 63;
                float a = tg[oc] * rsqrtf(1.f + 1e-5f);
                wb[idx] = f2bf(tcn_w[(oc * 64 + ci) * 9 + kt] * a);
            } else if (idx < 32768) {
                int i2 = idx - 27648;
                int r = i2 >> 6, c = i2 & 63;
                int src; float sc;
                if (r < 16)      { src = r;      sc = RS2_; }
                else if (r < 32) { src = r;      sc = SCALE_K; }
                else if (r < 48) { src = r + 16; sc = 1.f; }
                else if (r < 64) { src = r - 48; sc = RS2_; }
                else             { src = r - 48; sc = SCALE_K; }
                wq[i2] = f2bf(qkv_w[src * 64 + c] * sc);
            } else if (idx < 32848) {
                int r = idx - 32768;
                int src; float sc;
                if (r < 16)      { src = r;      sc = RS2_; }
                else if (r < 32) { src = r;      sc = SCALE_K; }
                else if (r < 48) { src = r + 16; sc = 1.f; }
                else if (r < 64) { src = r - 48; sc = RS2_; }
                else             { src = r - 48; sc = SCALE_K; }
                qb[r] = qkv_b[src] * sc;
            } else if (idx < 135248) {
                int i3 = idx - 32848;
                int ci = i3 / 1600, tv = i3 - ci * 1600;
                pet[tv * 64 + ci] = f2bf(pe[ci * 1600 + tv]);
            }
        }
        return;
    }
    if (bx == 26) {
        const int n = by;
        #pragma unroll
        for (int it = 0; it < 2; ++it) {
            int item = tid + it * 256;
            int ci = item >> 3, slot = item & 7;
            int t = (slot < 4) ? slot : (56 + slot);
            const float* xp = x + (n * 64 + ci) * TV_ + t * 25;
            float s = 0.f;
            #pragma unroll
            for (int v = 0; v < 25; ++v) s += xp[v];
            Tt[(n * 64 + ci) * 8 + slot] = s;
        }
        return;
    }

    __shared__ ushort smt[64 * 66];
    const int tv0 = bx * 64;
    const int n = by;
    const int tvl = tid & 63, cig = tid >> 6;
    const int tv = tv0 + tvl;

    float psum[16];
    #pragma unroll
    for (int k = 0; k < 16; ++k) psum[k] = 0.f;
    #pragma unroll
    for (int k = 0; k < 16; ++k) {
        int ci = k * 4 + cig;
        float xv = x[(n * 64 + ci) * TV_ + tv];
        smt[tvl * 66 + ci] = f2bf(xv);
        psum[k] += xv;
    }
    #pragma unroll
    for (int k = 0; k < 16; ++k) {
        float s = psum[k];
        #pragma unroll
        for (int off = 32; off >= 1; off >>= 1) s += __shfl_down(s, off, 64);
        if (tvl == 0) atomicAdd(&Sbuf[n * 64 + k * 4 + cig], s);
    }
    __syncthreads();

    #pragma unroll
    for (int j = 0; j < 8; ++j) {
        int chunk = tid + j * 256;
        int tvr = chunk >> 5, p = chunk & 31;
        uint val = *(const uint*)&smt[tvr * 66 + p * 2];
        *(uint*)&rt[(n * TV_ + tv0 + tvr) * 64 + p * 2] = val;
    }
}

// ---------------------------------------------------------------------------
// K1: score kernel per (n,v) — round-13 body; launch_bounds (256,6).
// ---------------------------------------------------------------------------
__global__ __launch_bounds__(256, 6) void score_kernel(
    const ushort* __restrict__ rt, const ushort* __restrict__ pet,
    const float* __restrict__ dbg, const float* __restrict__ dbb,
    const ushort* __restrict__ wq, const float* __restrict__ qb,
    const float* __restrict__ attn_w, const float* __restrict__ attn_b,
    float* __restrict__ aoc, float* __restrict__ se)
{
    __shared__ float sm[5312];
    ushort* smu = (ushort*)sm;
    const int MU_ = 1056, AO = 1120;
    const int FKP = 2400, PKP = 2976, FVP = 3552, PQP = 4128, FQP = 4704;

    const int b = blockIdx.x;
    const int l = b >> 3;
    const int n = (b & 7) * 8 + l / 25;
    const int v = l % 25;
    const int tid = threadIdx.x;

    const int lane = tid & 63, wave = tid >> 6;
    const int m16 = lane & 15, q = lane >> 4;

    {
        const int part = tid & 7;
        const int ci0 = part * 8;
        const float rs = rsqrtf(1.f + 1e-5f);
        float sc8[8], sh8[8];
        #pragma unroll
        for (int i = 0; i < 8; ++i) {
            sc8[i] = dbg[(ci0 + i) * 25 + v] * rs;
            sh8[i] = dbb[(ci0 + i) * 25 + v];
        }
        #pragma unroll
        for (int j = 0; j < 2; ++j) {
            int t = (tid + j * 256) >> 3;
            uint4 xr = *(const uint4*)&rt[(n * TV_ + t * 25 + v) * 64 + ci0];
            uint4 pr = *(const uint4*)&pet[(t * 25 + v) * 64 + ci0];
            const ushort* xu = (const ushort*)&xr;
            const ushort* pu = (const ushort*)&pr;
            ushort xs[8], ys[8];
            #pragma unroll
            for (int i = 0; i < 8; ++i) {
                float xf = bf2f(xu[i]);
                xs[i] = f2bf(xf * sc8[i] + sh8[i]);
                ys[i] = f2bf(xf + bf2f(pu[i]));
            }
            *(uint4*)&smu[t * 72 + ci0] = *(uint4*)xs;
            *(uint4*)&smu[4608 + t * 72 + ci0] = *(uint4*)ys;
        }
    }
    __syncthreads();

    f32x4 acc[5];
    #pragma unroll
    for (int mt = 0; mt < 5; ++mt) acc[mt] = (f32x4){0.f, 0.f, 0.f, 0.f};
    #pragma unroll
    for (int kt = 0; kt < 2; ++kt) {
        const int koff = kt * 32 + q * 8;
        bf16x8 bx = *(const bf16x8*)&smu[(wave * 16 + m16) * 72 + koff];
        bf16x8 by = *(const bf16x8*)&smu[4608 + (wave * 16 + m16) * 72 + koff];
        #pragma unroll
        for (int mt = 0; mt < 5; ++mt) {
            bf16x8 a = *(const bf16x8*)&wq[(mt * 16 + m16) * 64 + koff];
            acc[mt] = __builtin_amdgcn_mfma_f32_16x16x32_bf16(a, (mt < 3) ? bx : by, acc[mt], 0, 0, 0);
        }
    }
    __syncthreads();

    {
        const int t = wave * 16 + m16;
        #pragma unroll
        for (int r = 0; r < 4; ++r)
            sm[(q * 4 + r) * 66 + t] = acc[0][r] + qb[q * 4 + r];
        *(h2f*)&sm[FKP + t * 9 + 2 * q] =
            __builtin_amdgcn_cvt_pkrtz(acc[1][0] + qb[16 + q * 4], acc[1][1] + qb[16 + q * 4 + 1]);
        *(h2f*)&sm[FKP + t * 9 + 2 * q + 1] =
            __builtin_amdgcn_cvt_pkrtz(acc[1][2] + qb[16 + q * 4 + 2], acc[1][3] + qb[16 + q * 4 + 3]);
        *(h2f*)&sm[FVP + t * 9 + 2 * q] =
            __builtin_amdgcn_cvt_pkrtz(acc[2][0] + qb[32 + q * 4], acc[2][1] + qb[32 + q * 4 + 1]);
        *(h2f*)&sm[FVP + t * 9 + 2 * q + 1] =
            __builtin_amdgcn_cvt_pkrtz(acc[2][2] + qb[32 + q * 4 + 2], acc[2][3] + qb[32 + q * 4 + 3]);
        *(h2f*)&sm[PQP + t * 9 + 2 * q] =
            __builtin_amdgcn_cvt_pkrtz(acc[3][0] + qb[48 + q * 4], acc[3][1] + qb[48 + q * 4 + 1]);
        *(h2f*)&sm[PQP + t * 9 + 2 * q + 1] =
            __builtin_amdgcn_cvt_pkrtz(acc[3][2] + qb[48 + q * 4 + 2], acc[3][3] + qb[48 + q * 4 + 3]);
        *(h2f*)&sm[PKP + t * 9 + 2 * q] =
            __builtin_amdgcn_cvt_pkrtz(acc[4][0] + qb[64 + q * 4], acc[4][1] + qb[64 + q * 4 + 1]);
        *(h2f*)&sm[PKP + t * 9 + 2 * q + 1] =
            __builtin_amdgcn_cvt_pkrtz(acc[4][2] + qb[64 + q * 4 + 2], acc[4][3] + qb[64 + q * 4 + 3]);
    }
    __syncthreads();

    if (tid < 64) {
        int ch = tid & 15, qq = tid >> 4;
        float s = 0.f;
        #pragma unroll
        for (int t = 0; t < 16; ++t) s += sm[ch * 66 + qq * 16 + t];
        sm[MU_ + qq * 16 + ch] = s;
    }
    __syncthreads();
    if (tid < 16) {
        float mval = (sm[MU_ + tid] + sm[MU_ + 16 + tid] + sm[MU_ + 32 + tid] + sm[MU_ + 48 + tid]) * (1.f / 64.f);
        sm[MU_ + tid] = mval;
    }
    __syncthreads();

    #pragma unroll
    for (int e = 0; e < 2; ++e) {
        int idx = tid * 2 + e;
        int s = idx >> 3, h = idx & 7;
        float a = sm[(2 * h) * 66 + s] - sm[MU_ + 2 * h];
        float c = sm[(2 * h + 1) * 66 + s] - sm[MU_ + 2 * h + 1];
        *(h2f*)&sm[FQP + s * 9 + h] = __builtin_amdgcn_cvt_pkrtz(a, c);
    }
    __syncthreads();

    const int g3 = tid & 7, m3 = tid >> 3;
    #pragma unroll 1
    for (int h = 0; h < 8; ++h) {
        const float mu0 = sm[MU_ + 2 * h], mu1 = sm[MU_ + 2 * h + 1];
        float fq0c[2], fq1c[2], pq0[2], pq1[2];
        #pragma unroll
        for (int js = 0; js < 2; ++js) {
            int s = 2 * m3 + js;
            h2f fq2 = *(const h2f*)&sm[FQP + s * 9 + h];
            h2f pq2 = *(const h2f*)&sm[PQP + s * 9 + h];
            fq0c[js] = (float)fq2.x; fq1c[js] = (float)fq2.y;
            pq0[js] = (float)pq2.x;  pq1[js] = (float)pq2.y;
        }
        float ao00 = 0.f, ao01 = 0.f, ao10 = 0.f, ao11 = 0.f;
        #pragma unroll
        for (int ch = 0; ch < 2; ++ch) {
            float fk0[4], fk1[4], pk0[4], pk1[4], fv0[4], fv1[4], un[4];
            #pragma unroll
            for (int j = 0; j < 4; ++j) {
                int t = 8 * g3 + ch * 4 + j;
                h2f fk2 = *(const h2f*)&sm[FKP + t * 9 + h];
                h2f pk2 = *(const h2f*)&sm[PKP + t * 9 + h];
                h2f fv2 = *(const h2f*)&sm[FVP + t * 9 + h];
                fk0[j] = (float)fk2.x; fk1[j] = (float)fk2.y;
                pk0[j] = (float)pk2.x; pk1[j] = (float)pk2.y;
                fv0[j] = (float)fv2.x; fv1[j] = (float)fv2.y;
                un[j] = mu0 * fk0[j] + mu1 * fk1[j];
            }
            #pragma unroll
            for (int js = 0; js < 2; ++js) {
                #pragma unroll
                for (int j = 0; j < 4; ++j) {
                    float lp = pq0[js] * pk0[j] + pq1[js] * pk1[j];
                    float a1 = fq0c[js] * fk0[j] + fq1c[js] * fk1[j] + lp;
                    float a2 = un[j] + lp;
                    float w = tanh_scaled(a1) + tanh_scaled(a2);
                    if (js == 0) { ao00 += w * fv0[j]; ao01 += w * fv1[j]; }
                    else         { ao10 += w * fv0[j]; ao11 += w * fv1[j]; }
                }
            }
        }
        #pragma unroll
        for (int off = 1; off <= 4; off <<= 1) {
            ao00 += __shfl_xor(ao00, off);
            ao01 += __shfl_xor(ao01, off);
            ao10 += __shfl_xor(ao10, off);
            ao11 += __shfl_xor(ao11, off);
        }
        if (g3 == 0) {
            sm[AO + (2 * m3) * 20 + 2 * h]         = ao00;
            sm[AO + (2 * m3) * 20 + 2 * h + 1]     = ao01;
            sm[AO + (2 * m3 + 1) * 20 + 2 * h]     = ao10;
            sm[AO + (2 * m3 + 1) * 20 + 2 * h + 1] = ao11;
        }
    }
    __syncthreads();

    const int t = tid & 63, oq = tid >> 6;
    float aorow[16];
    #pragma unroll
    for (int i = 0; i < 4; ++i)
        *(float4*)&aorow[i * 4] = *(const float4*)&sm[AO + t * 20 + i * 4];
    float* aop = aoc + (n * 25 + v) * 1024;
    #pragma unroll
    for (int j = 0; j < 4; ++j) {
        int o = oq * 4 + j;
        float acc4 = attn_b[o];
        #pragma unroll
        for (int c = 0; c < 16; ++c) acc4 += attn_w[o * 16 + c] * aorow[c];
        aop[o * 64 + t] = acc4;
        float ssum = acc4;
        #pragma unroll
        for (int off = 32; off >= 1; off >>= 1) ssum += __shfl_down(ssum, off, 64);
        if ((tid & 63) == 0) atomicAdd(&se[n * 64 + 48 + o], ssum);
    }
}

// ---------------------------------------------------------------------------
// K2: tcn MFMA with INLINE analytic gate (gate_kernel dispatch eliminated).
// Each block computes its n's gate (432 parallel (oc,kt) dot-tasks); tile==0
// publishes gate to ws for final. Epilogue fuses gate+BN+ReLU for c<48.
// ---------------------------------------------------------------------------
__global__ __launch_bounds__(512, 1) void tcn_mfma_kernel(
    const ushort* __restrict__ rt, const float* __restrict__ x,
    const ushort* __restrict__ wb,
    const float* __restrict__ tcn_b, const float* __restrict__ tg,
    const float* __restrict__ tb,
    const float* __restrict__ se, const float* __restrict__ Sbuf,
    const float* __restrict__ Tt,
    const float* __restrict__ fc1w, const float* __restrict__ fc1b,
    const float* __restrict__ fc2w, const float* __restrict__ fc2b,
    const float* __restrict__ bng, const float* __restrict__ bnb,
    float* __restrict__ gate_out, float* __restrict__ out)
{
    __shared__ ushort xsl[600 * 72];
    __shared__ float U[576];        // [ci][kt] at ci*9+kt
    __shared__ float gpart[432];
    __shared__ float seL[64], hid[32], gateL[64];

    const int b = blockIdx.x;
    const int n = b >> 2, tile = b & 3;
    const int t0 = tile * 16;
    const int tid = threadIdx.x;
    const float rsbn = rsqrtf(1.f + 1e-5f);

    // staging (issues loads; completion ordered by the gate-phase barriers)
    const int tvbase = (t0 - 4) * 25;
    for (int idx = tid; idx < 4800; idx += 512) {
        int r = idx >> 3, part = idx & 7;
        int tv = tvbase + r;
        uint4 val = make_uint4(0u, 0u, 0u, 0u);
        if (tv >= 0 && tv < TV_) val = *(const uint4*)&rt[(n * TV_ + tv) * 64 + part * 8];
        *(uint4*)&xsl[r * 72 + part * 8] = val;
    }

    // inline gate: U table
    if (tid < 64) {
        float S = Sbuf[n * 64 + tid];
        float T[8];
        #pragma unroll
        for (int j = 0; j < 8; ++j) T[j] = Tt[(n * 64 + tid) * 8 + j];
        U[tid * 9 + 0] = S - (T[4] + T[5] + T[6] + T[7]);
        U[tid * 9 + 1] = S - (T[5] + T[6] + T[7]);
        U[tid * 9 + 2] = S - (T[6] + T[7]);
        U[tid * 9 + 3] = S - T[7];
        U[tid * 9 + 4] = S;
        U[tid * 9 + 5] = S - T[0];
        U[tid * 9 + 6] = S - (T[0] + T[1]);
        U[tid * 9 + 7] = S - (T[0] + T[1] + T[2]);
        U[tid * 9 + 8] = S - (T[0] + T[1] + T[2] + T[3]);
    }
    __syncthreads();
    if (tid < 432) {
        int oc = tid / 9, kt = tid - oc * 9;
        float cs = 0.f;
        #pragma unroll
        for (int cb = 0; cb < 8; ++cb) {
            bf16x8 w8 = *(const bf16x8*)&wb[oc * 576 + kt * 64 + cb * 8];
            #pragma unroll
            for (int i = 0; i < 8; ++i)
                cs += bf2f((ushort)w8[i]) * U[(cb * 8 + i) * 9 + kt];
        }
        gpart[tid] = cs;
    }
    __syncthreads();
    if (tid < 64) {
        if (tid < 48) {
            float cs = 0.f;
            #pragma unroll
            for (int kt = 0; kt < 9; ++kt) cs += gpart[tid * 9 + kt];
            float a = tg[tid] * rsbn;
            float cb_ = tcn_b[tid] * a + tb[tid];
            seL[tid] = (a * cs + 1600.f * cb_ + Sbuf[n * 64 + tid]) * (1.f / 1600.f);
        } else {
            seL[tid] = (se[n * 64 + tid] + Sbuf[n * 64 + tid]) * (1.f / 1600.f);
        }
    }
    __syncthreads();
    if (tid < 32) {
        float a = fc1b[tid];
        #pragma unroll
        for (int c = 0; c < 64; ++c) a += fc1w[tid * 64 + c] * seL[c];
        hid[tid] = fmaxf(a, 0.f);
    }
    __syncthreads();
    if (tid < 64) {
        float g = fc2b[tid];
        #pragma unroll
        for (int j = 0; j < 32; ++j) g += fc2w[tid * 32 + j] * hid[j];
        float gv = 1.f / (1.f + __expf(-g));
        gateL[tid] = gv;
        if (tile == 0) gate_out[n * 64 + tid] = gv;
    }
    __syncthreads();    // gate done AND staging complete

    const int lane = tid & 63, wave = tid >> 6;
    const int m16 = lane & 15, q = lane >> 4;
    const int nt0 = wave * 3;

    f32x4 acc[3][3];
    f32x4 acc24[3];
    #pragma unroll
    for (int i = 0; i < 3; ++i)
        #pragma unroll
        for (int mt = 0; mt < 3; ++mt)
            acc[i][mt] = (f32x4){0.f, 0.f, 0.f, 0.f};
    #pragma unroll
    for (int mt = 0; mt < 3; ++mt) acc24[mt] = (f32x4){0.f, 0.f, 0.f, 0.f};

    for (int ktile = 0; ktile < 18; ++ktile) {
        const int kt = ktile >> 1;
        const int cib = (ktile & 1) * 32 + q * 8;
        bf16x8 afr[3];
        #pragma unroll
        for (int mt = 0; mt < 3; ++mt)
            afr[mt] = *(const bf16x8*)&wb[(mt * 16 + m16) * 576 + ktile * 32 + q * 8];
        #pragma unroll
        for (int i = 0; i < 3; ++i) {
            int p = (nt0 + i) * 16 + m16;
            bf16x8 bfr = *(const bf16x8*)&xsl[(p + kt * 25) * 72 + cib];
            #pragma unroll
            for (int mt = 0; mt < 3; ++mt)
                acc[i][mt] = __builtin_amdgcn_mfma_f32_16x16x32_bf16(afr[mt], bfr, acc[i][mt], 0, 0, 0);
        }
        if (wave == 0) {
            int p = 24 * 16 + m16;
            bf16x8 bfr = *(const bf16x8*)&xsl[(p + kt * 25) * 72 + cib];
            #pragma unroll
            for (int mt = 0; mt < 3; ++mt)
                acc24[mt] = __builtin_amdgcn_mfma_f32_16x16x32_bf16(afr[mt], bfr, acc24[mt], 0, 0, 0);
        }
    }

    float cb3[3][4], m3_[3][4], bb3[3][4];
    #pragma unroll
    for (int mt = 0; mt < 3; ++mt)
        #pragma unroll
        for (int r = 0; r < 4; ++r) {
            int oc = mt * 16 + q * 4 + r;
            float a = tg[oc] * rsbn;
            cb3[mt][r] = tcn_b[oc] * a + tb[oc];
            m3_[mt][r] = (1.f + gateL[oc]) * (bng[oc] * rsbn);
            bb3[mt][r] = bnb[oc];
        }
    #pragma unroll
    for (int i = 0; i < 3; ++i) {
        int posg = tile * 400 + (nt0 + i) * 16 + m16;
        #pragma unroll
        for (int mt = 0; mt < 3; ++mt) {
            #pragma unroll
            for (int r = 0; r < 4; ++r) {
                int oc = mt * 16 + q * 4 + r;
                float val = acc[i][mt][r] + cb3[mt][r] + x[(n * 64 + oc) * TV_ + posg];
                out[(n * 64 + oc) * TV_ + posg] = fmaxf(val * m3_[mt][r] + bb3[mt][r], 0.f);
            }
        }
    }
    if (wave == 0) {
        int posg = tile * 400 + 24 * 16 + m16;
        #pragma unroll
        for (int mt = 0; mt < 3; ++mt) {
            #pragma unroll
            for (int r = 0; r < 4; ++r) {
                int oc = mt * 16 + q * 4 + r;
                float val = acc24[mt][r] + cb3[mt][r] + x[(n * 64 + oc) * TV_ + posg];
                out[(n * 64 + oc) * TV_ + posg] = fmaxf(val * m3_[mt][r] + bb3[mt][r], 0.f);
            }
        }
    }
}

// ---------------------------------------------------------------------------
// K4: final c>=48 via LDS transpose. Block = (n,o); loads 25 contiguous aoc
// rows coalesced, writes out rows coalesced with x residual. Grid 1024.
// ---------------------------------------------------------------------------
__global__ __launch_bounds__(256) void final_kernel(
    float* __restrict__ out, const float* __restrict__ aoc,
    const float* __restrict__ x, const float* __restrict__ gate,
    const float* __restrict__ bng, const float* __restrict__ bnb)
{
    __shared__ float ts[25 * 68];
    const int bx = blockIdx.x;
    const int o = bx & 15, n = bx >> 4;
    const int tid = threadIdx.x;
    const float rs = rsqrtf(1.f + 1e-5f);

    for (int task = tid; task < 400; task += 256) {
        int v = task >> 4, f = task & 15;
        float4 d = *(const float4*)&aoc[(n * 25 + v) * 1024 + o * 64 + f * 4];
        *(float4*)&ts[v * 68 + f * 4] = d;
    }
    __syncthreads();

    const float mm = (1.f + gate[n * 64 + 48 + o]) * (bng[48 + o] * rs);
    const float bb = bnb[48 + o];
    const int base4 = (n * 64 + 48 + o) * 400;
    for (int p4 = tid; p4 < 400; p4 += 256) {
        float4 xr = ((const float4*)x)[base4 + p4];
        float4 val;
        #pragma unroll
        for (int e = 0; e < 4; ++e) {
            int pos = p4 * 4 + e;
            int t = pos / 25, v = pos - t * 25;
            ((float*)&val)[e] = ts[v * 68 + t];
        }
        val.x = fmaxf((val.x + xr.x) * mm + bb, 0.f);
        val.y = fmaxf((val.y + xr.y) * mm + bb, 0.f);
        val.z = fmaxf((val.z + xr.z) * mm + bb, 0.f);
        val.w = fmaxf((val.w + xr.w) * mm + bb, 0.f);
        ((float4*)out)[base4 + p4] = val;
    }
}

extern "C" void kernel_launch(void* const* d_in, const int* in_sizes, int n_in,
                              void* d_out, int out_size, void* d_ws, size_t ws_size,
                              hipStream_t stream) {
    const float* x     = (const float*)d_in[0];
    const float* pe    = (const float*)d_in[1];
    const float* dbg   = (const float*)d_in[2];
    const float* dbb   = (const float*)d_in[3];
    const float* qkvw  = (const float*)d_in[4];
    const float* qkvb  = (const float*)d_in[5];
    const float* attnw = (const float*)d_in[6];
    const float* attnb = (const float*)d_in[7];
    const float* tcnw  = (const float*)d_in[8];
    const float* tcnb  = (const float*)d_in[9];
    const float* tcng  = (const float*)d_in[10];
    const float* tcnbb = (const float*)d_in[11];
    const float* fc1w  = (const float*)d_in[12];
    const float* fc1b  = (const float*)d_in[13];
    const float* fc2w  = (const float*)d_in[14];
    const float* fc2b  = (const float*)d_in[15];
    const float* bng   = (const float*)d_in[16];
    const float* bnb   = (const float*)d_in[17];

    float* out  = (float*)d_out;
    float* se   = (float*)d_ws;                      // 4096 f
    float* Sbuf = se + 4096;                         // 4096 f
    float* Tt   = Sbuf + 4096;                       // 32768 f
    float* gate = Tt + 32768;                        // 4096 f
    float* qb   = gate + 4096;                       // 96 f
    float* aoc  = qb + 96;                           // 1,638,400 f
    ushort* wb  = (ushort*)(aoc + 1638400);          // 27648 u16
    ushort* wq  = wb + 27648;                        // 5120 u16
    ushort* pet = wq + 5120;                         // 102,400 u16
    ushort* rt  = pet + 102400;                      // 6,553,600 u16

    hipMemsetAsync(se, 0, (4096 + 4096) * sizeof(float), stream);
    t1_kernel<<<dim3(27, 64), dim3(256), 0, stream>>>(
        x, pe, tcnw, tcng, qkvw, qkvb, rt, Sbuf, Tt, wb, wq, qb, pet);
    score_kernel<<<dim3(1600), dim3(256), 0, stream>>>(rt, pet, dbg, dbb, wq, qb, attnw, attnb, aoc, se);
    tcn_mfma_kernel<<<dim3(256), dim3(512), 0, stream>>>(
        rt, x, wb, tcnb, tcng, tcnbb, se, Sbuf, Tt,
        fc1w, fc1b, fc2w, fc2b, bng, bnb, gate, out);
    final_kernel<<<dim3(1024), dim3(256), 0, stream>>>(out, aoc, x, gate, bng, bnb);
}

// Round 15
// 207.392 us; speedup vs baseline: 1.3420x; 1.0608x over previous
//
#include <hip/hip_runtime.h>
#include <hip/hip_bf16.h>
#include <math.h>

#define TV_ 1600
#define SCALE_K 2.885390081777927f
#define RS2_ 0.70710678118654752f

typedef __attribute__((ext_vector_type(8))) short bf16x8;
typedef __attribute__((ext_vector_type(4))) float f32x4;
typedef __attribute__((ext_vector_type(2))) __fp16 h2f;

__device__ __forceinline__ float tanh_scaled(float y) {
    y = fminf(44.f, fmaxf(-44.f, y));
    float e = __builtin_amdgcn_exp2f(y);
    float r = __builtin_amdgcn_rcpf(e + 1.f);
    return __builtin_fmaf(e, r, -r);
}

__device__ __forceinline__ ushort f2bf(float f) {
    __hip_bfloat16 h = __float2bfloat16(f);
    return *(ushort*)&h;
}
__device__ __forceinline__ float bf2f(ushort u) {
    uint w = ((uint)u) << 16;
    return __uint_as_float(w);
}

// ---------------------------------------------------------------------------
// T1: bx<25 transpose -> rt + Sp partials (NO atomics -> no memset needed);
// bx==25 prep; bx==26 edge sums Tt.
// ---------------------------------------------------------------------------
__global__ __launch_bounds__(256) void t1_kernel(
    const float* __restrict__ x, const float* __restrict__ pe,
    const float* __restrict__ tcn_w, const float* __restrict__ tg,
    const float* __restrict__ qkv_w, const float* __restrict__ qkv_b,
    ushort* __restrict__ rt, float* __restrict__ Sp, float* __restrict__ Tt,
    ushort* __restrict__ wb, ushort* __restrict__ wq, float* __restrict__ qb,
    ushort* __restrict__ pet)
{
    const int tid = threadIdx.x;
    const int bx = blockIdx.x, by = blockIdx.y;

    if (bx == 25) {
        #pragma unroll 1
        for (int j = 0; j < 9; ++j) {
            int idx = by * 256 + tid + j * 16384;
            if (idx < 27648) {
                int oc = idx / 576, kk = idx - oc * 576;
                int kt = kk >> 6, ci = kk & 63;
                float a = tg[oc] * rsqrtf(1.f + 1e-5f);
                wb[idx] = f2bf(tcn_w[(oc * 64 + ci) * 9 + kt] * a);
            } else if (idx < 32768) {
                int i2 = idx - 27648;
                int r = i2 >> 6, c = i2 & 63;
                int src; float sc;
                if (r < 16)      { src = r;      sc = RS2_; }
                else if (r < 32) { src = r;      sc = SCALE_K; }
                else if (r < 48) { src = r + 16; sc = 1.f; }
                else if (r < 64) { src = r - 48; sc = RS2_; }
                else             { src = r - 48; sc = SCALE_K; }
                wq[i2] = f2bf(qkv_w[src * 64 + c] * sc);
            } else if (idx < 32848) {
                int r = idx - 32768;
                int src; float sc;
                if (r < 16)      { src = r;      sc = RS2_; }
                else if (r < 32) { src = r;      sc = SCALE_K; }
                else if (r < 48) { src = r + 16; sc = 1.f; }
                else if (r < 64) { src = r - 48; sc = RS2_; }
                else             { src = r - 48; sc = SCALE_K; }
                qb[r] = qkv_b[src] * sc;
            } else if (idx < 135248) {
                int i3 = idx - 32848;
                int ci = i3 / 1600, tv = i3 - ci * 1600;
                pet[tv * 64 + ci] = f2bf(pe[ci * 1600 + tv]);
            }
        }
        return;
    }
    if (bx == 26) {
        const int n = by;
        #pragma unroll
        for (int it = 0; it < 2; ++it) {
            int item = tid + it * 256;
            int ci = item >> 3, slot = item & 7;
            int t = (slot < 4) ? slot : (56 + slot);
            const float* xp = x + (n * 64 + ci) * TV_ + t * 25;
            float s = 0.f;
            #pragma unroll
            for (int v = 0; v < 25; ++v) s += xp[v];
            Tt[(n * 64 + ci) * 8 + slot] = s;
        }
        return;
    }

    __shared__ ushort smt[64 * 66];
    const int tv0 = bx * 64;
    const int n = by;
    const int tvl = tid & 63, cig = tid >> 6;
    const int tv = tv0 + tvl;

    float psum[16];
    #pragma unroll
    for (int k = 0; k < 16; ++k) psum[k] = 0.f;
    #pragma unroll
    for (int k = 0; k < 16; ++k) {
        int ci = k * 4 + cig;
        float xv = x[(n * 64 + ci) * TV_ + tv];
        smt[tvl * 66 + ci] = f2bf(xv);
        psum[k] += xv;
    }
    #pragma unroll
    for (int k = 0; k < 16; ++k) {
        float s = psum[k];
        #pragma unroll
        for (int off = 32; off >= 1; off >>= 1) s += __shfl_down(s, off, 64);
        if (tvl == 0) Sp[(n * 25 + bx) * 64 + k * 4 + cig] = s;
    }
    __syncthreads();

    #pragma unroll
    for (int j = 0; j < 8; ++j) {
        int chunk = tid + j * 256;
        int tvr = chunk >> 5, p = chunk & 31;
        uint val = *(const uint*)&smt[tvr * 66 + p * 2];
        *(uint*)&rt[(n * TV_ + tv0 + tvr) * 64 + p * 2] = val;
    }
}

// ---------------------------------------------------------------------------
// K1: score kernel per (n,v) — round-13 body, (256,5); phase-4 writes sep
// partials instead of se atomics.
// ---------------------------------------------------------------------------
__global__ __launch_bounds__(256, 5) void score_kernel(
    const ushort* __restrict__ rt, const ushort* __restrict__ pet,
    const float* __restrict__ dbg, const float* __restrict__ dbb,
    const ushort* __restrict__ wq, const float* __restrict__ qb,
    const float* __restrict__ attn_w, const float* __restrict__ attn_b,
    float* __restrict__ aoc, float* __restrict__ sep)
{
    __shared__ float sm[5312];
    ushort* smu = (ushort*)sm;
    const int MU_ = 1056, AO = 1120;
    const int FKP = 2400, PKP = 2976, FVP = 3552, PQP = 4128, FQP = 4704;

    const int b = blockIdx.x;
    const int l = b >> 3;
    const int n = (b & 7) * 8 + l / 25;
    const int v = l % 25;
    const int tid = threadIdx.x;

    const int lane = tid & 63, wave = tid >> 6;
    const int m16 = lane & 15, q = lane >> 4;

    {
        const int part = tid & 7;
        const int ci0 = part * 8;
        const float rs = rsqrtf(1.f + 1e-5f);
        float sc8[8], sh8[8];
        #pragma unroll
        for (int i = 0; i < 8; ++i) {
            sc8[i] = dbg[(ci0 + i) * 25 + v] * rs;
            sh8[i] = dbb[(ci0 + i) * 25 + v];
        }
        #pragma unroll
        for (int j = 0; j < 2; ++j) {
            int t = (tid + j * 256) >> 3;
            uint4 xr = *(const uint4*)&rt[(n * TV_ + t * 25 + v) * 64 + ci0];
            uint4 pr = *(const uint4*)&pet[(t * 25 + v) * 64 + ci0];
            const ushort* xu = (const ushort*)&xr;
            const ushort* pu = (const ushort*)&pr;
            ushort xs[8], ys[8];
            #pragma unroll
            for (int i = 0; i < 8; ++i) {
                float xf = bf2f(xu[i]);
                xs[i] = f2bf(xf * sc8[i] + sh8[i]);
                ys[i] = f2bf(xf + bf2f(pu[i]));
            }
            *(uint4*)&smu[t * 72 + ci0] = *(uint4*)xs;
            *(uint4*)&smu[4608 + t * 72 + ci0] = *(uint4*)ys;
        }
    }
    __syncthreads();

    f32x4 acc[5];
    #pragma unroll
    for (int mt = 0; mt < 5; ++mt) acc[mt] = (f32x4){0.f, 0.f, 0.f, 0.f};
    #pragma unroll
    for (int kt = 0; kt < 2; ++kt) {
        const int koff = kt * 32 + q * 8;
        bf16x8 bx = *(const bf16x8*)&smu[(wave * 16 + m16) * 72 + koff];
        bf16x8 by = *(const bf16x8*)&smu[4608 + (wave * 16 + m16) * 72 + koff];
        #pragma unroll
        for (int mt = 0; mt < 5; ++mt) {
            bf16x8 a = *(const bf16x8*)&wq[(mt * 16 + m16) * 64 + koff];
            acc[mt] = __builtin_amdgcn_mfma_f32_16x16x32_bf16(a, (mt < 3) ? bx : by, acc[mt], 0, 0, 0);
        }
    }
    __syncthreads();

    {
        const int t = wave * 16 + m16;
        #pragma unroll
        for (int r = 0; r < 4; ++r)
            sm[(q * 4 + r) * 66 + t] = acc[0][r] + qb[q * 4 + r];
        *(h2f*)&sm[FKP + t * 9 + 2 * q] =
            __builtin_amdgcn_cvt_pkrtz(acc[1][0] + qb[16 + q * 4], acc[1][1] + qb[16 + q * 4 + 1]);
        *(h2f*)&sm[FKP + t * 9 + 2 * q + 1] =
            __builtin_amdgcn_cvt_pkrtz(acc[1][2] + qb[16 + q * 4 + 2], acc[1][3] + qb[16 + q * 4 + 3]);
        *(h2f*)&sm[FVP + t * 9 + 2 * q] =
            __builtin_amdgcn_cvt_pkrtz(acc[2][0] + qb[32 + q * 4], acc[2][1] + qb[32 + q * 4 + 1]);
        *(h2f*)&sm[FVP + t * 9 + 2 * q + 1] =
            __builtin_amdgcn_cvt_pkrtz(acc[2][2] + qb[32 + q * 4 + 2], acc[2][3] + qb[32 + q * 4 + 3]);
        *(h2f*)&sm[PQP + t * 9 + 2 * q] =
            __builtin_amdgcn_cvt_pkrtz(acc[3][0] + qb[48 + q * 4], acc[3][1] + qb[48 + q * 4 + 1]);
        *(h2f*)&sm[PQP + t * 9 + 2 * q + 1] =
            __builtin_amdgcn_cvt_pkrtz(acc[3][2] + qb[48 + q * 4 + 2], acc[3][3] + qb[48 + q * 4 + 3]);
        *(h2f*)&sm[PKP + t * 9 + 2 * q] =
            __builtin_amdgcn_cvt_pkrtz(acc[4][0] + qb[64 + q * 4], acc[4][1] + qb[64 + q * 4 + 1]);
        *(h2f*)&sm[PKP + t * 9 + 2 * q + 1] =
            __builtin_amdgcn_cvt_pkrtz(acc[4][2] + qb[64 + q * 4 + 2], acc[4][3] + qb[64 + q * 4 + 3]);
    }
    __syncthreads();

    if (tid < 64) {
        int ch = tid & 15, qq = tid >> 4;
        float s = 0.f;
        #pragma unroll
        for (int t = 0; t < 16; ++t) s += sm[ch * 66 + qq * 16 + t];
        sm[MU_ + qq * 16 + ch] = s;
    }
    __syncthreads();
    if (tid < 16) {
        float mval = (sm[MU_ + tid] + sm[MU_ + 16 + tid] + sm[MU_ + 32 + tid] + sm[MU_ + 48 + tid]) * (1.f / 64.f);
        sm[MU_ + tid] = mval;
    }
    __syncthreads();

    #pragma unroll
    for (int e = 0; e < 2; ++e) {
        int idx = tid * 2 + e;
        int s = idx >> 3, h = idx & 7;
        float a = sm[(2 * h) * 66 + s] - sm[MU_ + 2 * h];
        float c = sm[(2 * h + 1) * 66 + s] - sm[MU_ + 2 * h + 1];
        *(h2f*)&sm[FQP + s * 9 + h] = __builtin_amdgcn_cvt_pkrtz(a, c);
    }
    __syncthreads();

    const int g3 = tid & 7, m3 = tid >> 3;
    #pragma unroll 1
    for (int h = 0; h < 8; ++h) {
        const float mu0 = sm[MU_ + 2 * h], mu1 = sm[MU_ + 2 * h + 1];
        float fq0c[2], fq1c[2], pq0[2], pq1[2];
        #pragma unroll
        for (int js = 0; js < 2; ++js) {
            int s = 2 * m3 + js;
            h2f fq2 = *(const h2f*)&sm[FQP + s * 9 + h];
            h2f pq2 = *(const h2f*)&sm[PQP + s * 9 + h];
            fq0c[js] = (float)fq2.x; fq1c[js] = (float)fq2.y;
            pq0[js] = (float)pq2.x;  pq1[js] = (float)pq2.y;
        }
        float ao00 = 0.f, ao01 = 0.f, ao10 = 0.f, ao11 = 0.f;
        #pragma unroll
        for (int ch = 0; ch < 2; ++ch) {
            float fk0[4], fk1[4], pk0[4], pk1[4], fv0[4], fv1[4], un[4];
            #pragma unroll
            for (int j = 0; j < 4; ++j) {
                int t = 8 * g3 + ch * 4 + j;
                h2f fk2 = *(const h2f*)&sm[FKP + t * 9 + h];
                h2f pk2 = *(const h2f*)&sm[PKP + t * 9 + h];
                h2f fv2 = *(const h2f*)&sm[FVP + t * 9 + h];
                fk0[j] = (float)fk2.x; fk1[j] = (float)fk2.y;
                pk0[j] = (float)pk2.x; pk1[j] = (float)pk2.y;
                fv0[j] = (float)fv2.x; fv1[j] = (float)fv2.y;
                un[j] = mu0 * fk0[j] + mu1 * fk1[j];
            }
            #pragma unroll
            for (int js = 0; js < 2; ++js) {
                #pragma unroll
                for (int j = 0; j < 4; ++j) {
                    float lp = pq0[js] * pk0[j] + pq1[js] * pk1[j];
                    float a1 = fq0c[js] * fk0[j] + fq1c[js] * fk1[j] + lp;
                    float a2 = un[j] + lp;
                    float w = tanh_scaled(a1) + tanh_scaled(a2);
                    if (js == 0) { ao00 += w * fv0[j]; ao01 += w * fv1[j]; }
                    else         { ao10 += w * fv0[j]; ao11 += w * fv1[j]; }
                }
            }
        }
        #pragma unroll
        for (int off = 1; off <= 4; off <<= 1) {
            ao00 += __shfl_xor(ao00, off);
            ao01 += __shfl_xor(ao01, off);
            ao10 += __shfl_xor(ao10, off);
            ao11 += __shfl_xor(ao11, off);
        }
        if (g3 == 0) {
            sm[AO + (2 * m3) * 20 + 2 * h]         = ao00;
            sm[AO + (2 * m3) * 20 + 2 * h + 1]     = ao01;
            sm[AO + (2 * m3 + 1) * 20 + 2 * h]     = ao10;
            sm[AO + (2 * m3 + 1) * 20 + 2 * h + 1] = ao11;
        }
    }
    __syncthreads();

    const int t = tid & 63, oq = tid >> 6;
    float aorow[16];
    #pragma unroll
    for (int i = 0; i < 4; ++i)
        *(float4*)&aorow[i * 4] = *(const float4*)&sm[AO + t * 20 + i * 4];
    float* aop = aoc + (n * 25 + v) * 1024;
    #pragma unroll
    for (int j = 0; j < 4; ++j) {
        int o = oq * 4 + j;
        float acc4 = attn_b[o];
        #pragma unroll
        for (int c = 0; c < 16; ++c) acc4 += attn_w[o * 16 + c] * aorow[c];
        aop[o * 64 + t] = acc4;
        float ssum = acc4;
        #pragma unroll
        for (int off = 32; off >= 1; off >>= 1) ssum += __shfl_down(ssum, off, 64);
        if ((tid & 63) == 0) sep[(n * 25 + v) * 16 + o] = ssum;
    }
}

// ---------------------------------------------------------------------------
// K2: tcn MFMA + inline analytic gate + MERGED final (c>=48) phase.
// 3-dispatch pipeline: t1 -> score -> tcn. tcn writes ALL of out.
// ---------------------------------------------------------------------------
__global__ __launch_bounds__(512, 1) void tcn_mfma_kernel(
    const ushort* __restrict__ rt, const float* __restrict__ x,
    const ushort* __restrict__ wb,
    const float* __restrict__ tcn_b, const float* __restrict__ tg,
    const float* __restrict__ tb,
    const float* __restrict__ sep, const float* __restrict__ Sp,
    const float* __restrict__ Tt, const float* __restrict__ aoc,
    const float* __restrict__ fc1w, const float* __restrict__ fc1b,
    const float* __restrict__ fc2w, const float* __restrict__ fc2b,
    const float* __restrict__ bng, const float* __restrict__ bnb,
    float* __restrict__ out)
{
    __shared__ ushort xsl[600 * 72];
    __shared__ float U[576];
    __shared__ float gpart[432];
    __shared__ float SS[64], seL[64], hid[32], gateL[64];

    const int b = blockIdx.x;
    const int n = b >> 2, tile = b & 3;
    const int t0 = tile * 16;
    const int tid = threadIdx.x;
    const float rsbn = rsqrtf(1.f + 1e-5f);

    const int tvbase = (t0 - 4) * 25;
    for (int idx = tid; idx < 4800; idx += 512) {
        int r = idx >> 3, part = idx & 7;
        int tv = tvbase + r;
        uint4 val = make_uint4(0u, 0u, 0u, 0u);
        if (tv >= 0 && tv < TV_) val = *(const uint4*)&rt[(n * TV_ + tv) * 64 + part * 8];
        *(uint4*)&xsl[r * 72 + part * 8] = val;
    }

    // inline gate: S from Sp partials, U table
    if (tid < 64) {
        float S = 0.f;
        #pragma unroll 1
        for (int j = 0; j < 25; ++j) S += Sp[(n * 25 + j) * 64 + tid];
        SS[tid] = S;
        float T[8];
        #pragma unroll
        for (int j = 0; j < 8; ++j) T[j] = Tt[(n * 64 + tid) * 8 + j];
        U[tid * 9 + 0] = S - (T[4] + T[5] + T[6] + T[7]);
        U[tid * 9 + 1] = S - (T[5] + T[6] + T[7]);
        U[tid * 9 + 2] = S - (T[6] + T[7]);
        U[tid * 9 + 3] = S - T[7];
        U[tid * 9 + 4] = S;
        U[tid * 9 + 5] = S - T[0];
        U[tid * 9 + 6] = S - (T[0] + T[1]);
        U[tid * 9 + 7] = S - (T[0] + T[1] + T[2]);
        U[tid * 9 + 8] = S - (T[0] + T[1] + T[2] + T[3]);
    }
    __syncthreads();
    if (tid < 432) {
        int oc = tid / 9, kt = tid - oc * 9;
        float cs = 0.f;
        #pragma unroll
        for (int cb = 0; cb < 8; ++cb) {
            bf16x8 w8 = *(const bf16x8*)&wb[oc * 576 + kt * 64 + cb * 8];
            #pragma unroll
            for (int i = 0; i < 8; ++i)
                cs += bf2f((ushort)w8[i]) * U[(cb * 8 + i) * 9 + kt];
        }
        gpart[tid] = cs;
    }
    __syncthreads();
    if (tid < 64) {
        if (tid < 48) {
            float cs = 0.f;
            #pragma unroll
            for (int kt = 0; kt < 9; ++kt) cs += gpart[tid * 9 + kt];
            float a = tg[tid] * rsbn;
            float cb_ = tcn_b[tid] * a + tb[tid];
            seL[tid] = (a * cs + 1600.f * cb_ + SS[tid]) * (1.f / 1600.f);
        } else {
            float at = 0.f;
            #pragma unroll 1
            for (int j = 0; j < 25; ++j) at += sep[(n * 25 + j) * 16 + tid - 48];
            seL[tid] = (at + SS[tid]) * (1.f / 1600.f);
        }
    }
    __syncthreads();
    if (tid < 32) {
        float a = fc1b[tid];
        #pragma unroll
        for (int c = 0; c < 64; ++c) a += fc1w[tid * 64 + c] * seL[c];
        hid[tid] = fmaxf(a, 0.f);
    }
    __syncthreads();
    if (tid < 64) {
        float g = fc2b[tid];
        #pragma unroll
        for (int j = 0; j < 32; ++j) g += fc2w[tid * 32 + j] * hid[j];
        gateL[tid] = 1.f / (1.f + __expf(-g));
    }
    __syncthreads();

    const int lane = tid & 63, wave = tid >> 6;
    const int m16 = lane & 15, q = lane >> 4;
    const int nt0 = wave * 3;

    f32x4 acc[3][3];
    f32x4 acc24[3];
    #pragma unroll
    for (int i = 0; i < 3; ++i)
        #pragma unroll
        for (int mt = 0; mt < 3; ++mt)
            acc[i][mt] = (f32x4){0.f, 0.f, 0.f, 0.f};
    #pragma unroll
    for (int mt = 0; mt < 3; ++mt) acc24[mt] = (f32x4){0.f, 0.f, 0.f, 0.f};

    for (int ktile = 0; ktile < 18; ++ktile) {
        const int kt = ktile >> 1;
        const int cib = (ktile & 1) * 32 + q * 8;
        bf16x8 afr[3];
        #pragma unroll
        for (int mt = 0; mt < 3; ++mt)
            afr[mt] = *(const bf16x8*)&wb[(mt * 16 + m16) * 576 + ktile * 32 + q * 8];
        #pragma unroll
        for (int i = 0; i < 3; ++i) {
            int p = (nt0 + i) * 16 + m16;
            bf16x8 bfr = *(const bf16x8*)&xsl[(p + kt * 25) * 72 + cib];
            #pragma unroll
            for (int mt = 0; mt < 3; ++mt)
                acc[i][mt] = __builtin_amdgcn_mfma_f32_16x16x32_bf16(afr[mt], bfr, acc[i][mt], 0, 0, 0);
        }
        if (wave == 0) {
            int p = 24 * 16 + m16;
            bf16x8 bfr = *(const bf16x8*)&xsl[(p + kt * 25) * 72 + cib];
            #pragma unroll
            for (int mt = 0; mt < 3; ++mt)
                acc24[mt] = __builtin_amdgcn_mfma_f32_16x16x32_bf16(afr[mt], bfr, acc24[mt], 0, 0, 0);
        }
    }

    float cb3[3][4], m3_[3][4], bb3[3][4];
    #pragma unroll
    for (int mt = 0; mt < 3; ++mt)
        #pragma unroll
        for (int r = 0; r < 4; ++r) {
            int oc = mt * 16 + q * 4 + r;
            float a = tg[oc] * rsbn;
            cb3[mt][r] = tcn_b[oc] * a + tb[oc];
            m3_[mt][r] = (1.f + gateL[oc]) * (bng[oc] * rsbn);
            bb3[mt][r] = bnb[oc];
        }
    #pragma unroll
    for (int i = 0; i < 3; ++i) {
        int posg = tile * 400 + (nt0 + i) * 16 + m16;
        #pragma unroll
        for (int mt = 0; mt < 3; ++mt) {
            #pragma unroll
            for (int r = 0; r < 4; ++r) {
                int oc = mt * 16 + q * 4 + r;
                float val = acc[i][mt][r] + cb3[mt][r] + x[(n * 64 + oc) * TV_ + posg];
                out[(n * 64 + oc) * TV_ + posg] = fmaxf(val * m3_[mt][r] + bb3[mt][r], 0.f);
            }
        }
    }
    if (wave == 0) {
        int posg = tile * 400 + 24 * 16 + m16;
        #pragma unroll
        for (int mt = 0; mt < 3; ++mt) {
            #pragma unroll
            for (int r = 0; r < 4; ++r) {
                int oc = mt * 16 + q * 4 + r;
                float val = acc24[mt][r] + cb3[mt][r] + x[(n * 64 + oc) * TV_ + posg];
                out[(n * 64 + oc) * TV_ + posg] = fmaxf(val * m3_[mt][r] + bb3[mt][r], 0.f);
            }
        }
    }

    // merged final phase: c>=48, this block's (n, t-range tile*16..tile*16+15)
    __syncthreads();                 // xsl dead -> reuse as ts[v][o][lt], stride 257
    float* ts = (float*)xsl;         // 25*257 = 6425 floats
    for (int task = tid; task < 1600; task += 512) {
        int v = task >> 6;           // 0..24
        int r = task & 63;
        int o = r >> 2, f = r & 3;
        float4 d = *(const float4*)&aoc[(n * 25 + v) * 1024 + o * 64 + tile * 16 + f * 4];
        float* dst = &ts[v * 257 + o * 16 + f * 4];
        dst[0] = d.x; dst[1] = d.y; dst[2] = d.z; dst[3] = d.w;
    }
    __syncthreads();
    for (int p4 = tid; p4 < 1600; p4 += 512) {   // 16 o x 100 float4
        int o = p4 / 100, r4 = p4 - o * 100;
        int base4 = (n * 64 + 48 + o) * 400 + tile * 100 + r4;
        float4 xr = ((const float4*)x)[base4];
        float4 val;
        #pragma unroll
        for (int e = 0; e < 4; ++e) {
            int pos = r4 * 4 + e;                // 0..399 within tile
            int lt = pos / 25, v = pos - lt * 25;
            ((float*)&val)[e] = ts[v * 257 + o * 16 + lt];
        }
        float mm = (1.f + gateL[48 + o]) * (bng[48 + o] * rsbn);
        float bb = bnb[48 + o];
        val.x = fmaxf((val.x + xr.x) * mm + bb, 0.f);
        val.y = fmaxf((val.y + xr.y) * mm + bb, 0.f);
        val.z = fmaxf((val.z + xr.z) * mm + bb, 0.f);
        val.w = fmaxf((val.w + xr.w) * mm + bb, 0.f);
        ((float4*)out)[base4] = val;
    }
}

extern "C" void kernel_launch(void* const* d_in, const int* in_sizes, int n_in,
                              void* d_out, int out_size, void* d_ws, size_t ws_size,
                              hipStream_t stream) {
    const float* x     = (const float*)d_in[0];
    const float* pe    = (const float*)d_in[1];
    const float* dbg   = (const float*)d_in[2];
    const float* dbb   = (const float*)d_in[3];
    const float* qkvw  = (const float*)d_in[4];
    const float* qkvb  = (const float*)d_in[5];
    const float* attnw = (const float*)d_in[6];
    const float* attnb = (const float*)d_in[7];
    const float* tcnw  = (const float*)d_in[8];
    const float* tcnb  = (const float*)d_in[9];
    const float* tcng  = (const float*)d_in[10];
    const float* tcnbb = (const float*)d_in[11];
    const float* fc1w  = (const float*)d_in[12];
    const float* fc1b  = (const float*)d_in[13];
    const float* fc2w  = (const float*)d_in[14];
    const float* fc2b  = (const float*)d_in[15];
    const float* bng   = (const float*)d_in[16];
    const float* bnb   = (const float*)d_in[17];

    float* out  = (float*)d_out;
    float* Sp   = (float*)d_ws;                      // 64*25*64 = 102400 f
    float* sep  = Sp + 102400;                       // 64*25*16 = 25600 f
    float* Tt   = sep + 25600;                       // 32768 f
    float* qb   = Tt + 32768;                        // 96 f
    float* aoc  = qb + 96;                           // 1,638,400 f
    ushort* wb  = (ushort*)(aoc + 1638400);          // 27648 u16
    ushort* wq  = wb + 27648;                        // 5120 u16
    ushort* pet = wq + 5120;                         // 102,400 u16
    ushort* rt  = pet + 102400;                      // 6,553,600 u16

    t1_kernel<<<dim3(27, 64), dim3(256), 0, stream>>>(
        x, pe, tcnw, tcng, qkvw, qkvb, rt, Sp, Tt, wb, wq, qb, pet);
    score_kernel<<<dim3(1600), dim3(256), 0, stream>>>(rt, pet, dbg, dbb, wq, qb, attnw, attnb, aoc, sep);
    tcn_mfma_kernel<<<dim3(256), dim3(512), 0, stream>>>(
        rt, x, wb, tcnb, tcng, tcnbb, sep, Sp, Tt, aoc,
        fc1w, fc1b, fc2w, fc2b, bng, bnb, out);
}